// Round 1
// baseline (1860.379 us; speedup 1.0000x reference)
//
#include <hip/hip_runtime.h>
#include <math.h>

#define TILE 16

// ---------------------------------------------------------------------------
// Kernel A: fused conv1(3->16,3x3,SAME) + relu + conv2(16->32,3x3,SAME) + relu
//           + spatial partial sum -> atomicAdd into feat_sum[B][32]
// One block = one (batch, 16x16 tile). 256 threads, thread = one output pixel.
// ---------------------------------------------------------------------------
__global__ __launch_bounds__(256) void conv_feat_kernel(
    const float* __restrict__ x,      // (64,3,256,256)
    const float* __restrict__ w1,     // (16,3,3,3)
    const float* __restrict__ b1,     // (16,)
    const float* __restrict__ w2,     // (32,16,3,3)
    const float* __restrict__ b2,     // (32,)
    float* __restrict__ feat_sum)     // (64,32) accumulated sum over H,W
{
    __shared__ float s_in[3][20][20];    // input tile, halo 2
    __shared__ float s_h1[16][18][18];   // conv1 output, halo 1
    __shared__ float s_w1[16][27];
    __shared__ float s_b1[16];
    __shared__ float s_w2[32][144];
    __shared__ float s_b2[32];
    __shared__ float s_part[4][32];

    const int t  = threadIdx.x;
    const int tx = blockIdx.x, ty = blockIdx.y, b = blockIdx.z;

    // stage weights
    for (int i = t; i < 16 * 27; i += 256) s_w1[i / 27][i % 27] = w1[i];
    for (int i = t; i < 32 * 144; i += 256) s_w2[i / 144][i % 144] = w2[i];
    if (t < 16) s_b1[t] = b1[t];
    if (t >= 32 && t < 64) s_b2[t - 32] = b2[t - 32];

    // stage input tile (halo 2), zero-padded at image border
    const int gy0 = ty * TILE - 2, gx0 = tx * TILE - 2;
    for (int i = t; i < 3 * 20 * 20; i += 256) {
        int c = i / 400, r = (i % 400) / 20, col = i % 20;
        int gy = gy0 + r, gx = gx0 + col;
        float v = 0.0f;
        if (gy >= 0 && gy < 256 && gx >= 0 && gx < 256)
            v = x[((b * 3 + c) * 256 + gy) * 256 + gx];
        s_in[c][r][col] = v;
    }
    __syncthreads();

    // conv1 + relu into s_h1 (positions outside the image forced to 0 so that
    // conv2's SAME zero-padding is honored)
    for (int i = t; i < 16 * 18 * 18; i += 256) {
        int oc = i / 324, rem = i % 324, y = rem / 18, xx = rem % 18;
        int gy = ty * TILE - 1 + y, gx = tx * TILE - 1 + xx;
        float acc = s_b1[oc];
#pragma unroll
        for (int c = 0; c < 3; ++c)
#pragma unroll
            for (int ky = 0; ky < 3; ++ky)
#pragma unroll
                for (int kx = 0; kx < 3; ++kx)
                    acc += s_in[c][y + ky][xx + kx] * s_w1[oc][c * 9 + ky * 3 + kx];
        acc = fmaxf(acc, 0.0f);
        if (gy < 0 || gy >= 256 || gx < 0 || gx >= 256) acc = 0.0f;
        s_h1[oc][y][xx] = acc;
    }
    __syncthreads();

    // conv2 + relu; thread t handles pixel (y,xx), all 32 output channels
    const int y = t / 16, xx = t % 16;
    float acc[32];
#pragma unroll
    for (int o = 0; o < 32; ++o) acc[o] = s_b2[o];

    for (int ic = 0; ic < 16; ++ic) {
        float win[9];
#pragma unroll
        for (int ky = 0; ky < 3; ++ky)
#pragma unroll
            for (int kx = 0; kx < 3; ++kx)
                win[ky * 3 + kx] = s_h1[ic][y + ky][xx + kx];
#pragma unroll
        for (int o = 0; o < 32; ++o) {
#pragma unroll
            for (int k = 0; k < 9; ++k)
                acc[o] += win[k] * s_w2[o][ic * 9 + k];
        }
    }
#pragma unroll
    for (int o = 0; o < 32; ++o) acc[o] = fmaxf(acc[o], 0.0f);

    // block reduction: wave shuffle -> LDS -> 32 atomics/block
    const int lane = t & 63, wv = t >> 6;
#pragma unroll
    for (int o = 0; o < 32; ++o) {
        float v = acc[o];
        for (int off = 32; off; off >>= 1) v += __shfl_xor(v, off);
        if (lane == 0) s_part[wv][o] = v;
    }
    __syncthreads();
    if (t < 32) {
        float s = s_part[0][t] + s_part[1][t] + s_part[2][t] + s_part[3][t];
        atomicAdd(feat_sum + b * 32 + t, s);
    }
}

// ---------------------------------------------------------------------------
// Kernel B: gating. One block per batch row, 64 threads (= experts, 1 wave).
// ---------------------------------------------------------------------------
__global__ __launch_bounds__(64) void router_gate_kernel(
    const int* __restrict__ task_id,    // (64,)
    const float* __restrict__ noise,    // (64,64)
    const float* __restrict__ mlp_w1,   // (1,32)
    const float* __restrict__ mlp_b1,   // (32,)
    const float* __restrict__ mlp_w2,   // (32,32)
    const float* __restrict__ mlp_b2,   // (32,)
    const float* __restrict__ deg_w,    // (32,32)
    const float* __restrict__ deg_b,    // (32,)
    const float* __restrict__ keys,     // (64,32)
    const float* __restrict__ gate_w,   // (64,64)
    const float* __restrict__ gate_b,   // (64,)
    const float* __restrict__ noise_w,  // (64,64)
    const float* __restrict__ noise_b,  // (64,)
    const float* __restrict__ feat_sum, // (64,32) spatial sums
    float* __restrict__ out)            // gates (64,64) then load (64,)
{
    const int b = blockIdx.x;
    const int e = threadIdx.x;  // 0..63

    __shared__ float s_te[32];
    __shared__ float s_comb[32];
    __shared__ float s_ew[64];

    if (e < 32) {
        float tf = (float)task_id[b];
        s_te[e] = fmaxf(tf * mlp_w1[e] + mlp_b1[e], 0.0f);
    }
    __syncthreads();
    if (e < 32) {
        float acc = mlp_b2[e];
        for (int k = 0; k < 32; ++k) acc += s_te[k] * mlp_w2[k * 32 + e];
        float dacc = deg_b[e];
        for (int c = 0; c < 32; ++c)
            dacc += (feat_sum[b * 32 + c] * (1.0f / 65536.0f)) * deg_w[c * 32 + e];
        s_comb[e] = acc + 0.2f * dacc;  // ALPHA = 0.8
    }
    __syncthreads();

    // sim + softmax over experts
    float s = 0.0f;
    for (int d = 0; d < 32; ++d) s += s_comb[d] * keys[e * 32 + d];
    s *= 0.17677669529663687f;  // 1/sqrt(32)

    float m = s;
    for (int off = 32; off; off >>= 1) m = fmaxf(m, __shfl_xor(m, off));
    float p = expf(s - m);
    float sum = p;
    for (int off = 32; off; off >>= 1) sum += __shfl_xor(sum, off);
    float w = p / sum;
    s_ew[e] = w;
    __syncthreads();

    // clean logits + noise stddev
    float cl = gate_b[e], nz = noise_b[e];
    for (int k = 0; k < 64; ++k) {
        float ewk = s_ew[k];
        cl += ewk * gate_w[k * 64 + e];
        nz += ewk * noise_w[k * 64 + e];
    }
    float sp = (nz > 20.0f) ? nz : log1pf(expf(nz));
    float logit = cl + noise[b * 64 + e] * (sp + 0.01f);

    // top-2 (ties -> lower index, matching lax.top_k)
    float v0 = logit; int i0 = e;
    for (int off = 32; off; off >>= 1) {
        float ov = __shfl_xor(v0, off);
        int   oi = __shfl_xor(i0, off);
        if (ov > v0 || (ov == v0 && oi < i0)) { v0 = ov; i0 = oi; }
    }
    float v1 = (e == i0) ? -INFINITY : logit; int i1 = e;
    for (int off = 32; off; off >>= 1) {
        float ov = __shfl_xor(v1, off);
        int   oi = __shfl_xor(i1, off);
        if (ov > v1 || (ov == v1 && oi < i1)) { v1 = ov; i1 = oi; }
    }

    // softmax over the two kept logits (v0 >= v1)
    float e1 = expf(v1 - v0);
    float g0 = 1.0f / (1.0f + e1);
    float g1 = e1 / (1.0f + e1);

    float g = (e == i0) ? g0 : (e == i1) ? g1 : 0.0f;
    out[b * 64 + e] = g;
    if (g != 0.0f) atomicAdd(out + 64 * 64 + e, g);  // load
}

extern "C" void kernel_launch(void* const* d_in, const int* in_sizes, int n_in,
                              void* d_out, int out_size, void* d_ws, size_t ws_size,
                              hipStream_t stream) {
    const int*   task_id = (const int*)d_in[0];
    const float* x       = (const float*)d_in[1];
    const float* noise   = (const float*)d_in[2];
    const float* mlp_w1  = (const float*)d_in[3];
    const float* mlp_b1  = (const float*)d_in[4];
    const float* mlp_w2  = (const float*)d_in[5];
    const float* mlp_b2  = (const float*)d_in[6];
    const float* conv1_w = (const float*)d_in[7];
    const float* conv1_b = (const float*)d_in[8];
    const float* conv2_w = (const float*)d_in[9];
    const float* conv2_b = (const float*)d_in[10];
    const float* deg_w   = (const float*)d_in[11];
    const float* deg_b   = (const float*)d_in[12];
    const float* keys    = (const float*)d_in[13];
    const float* gate_w  = (const float*)d_in[14];
    const float* gate_b  = (const float*)d_in[15];
    const float* noise_w = (const float*)d_in[16];
    const float* noise_b = (const float*)d_in[17];

    float* out  = (float*)d_out;
    float* feat = (float*)d_ws;  // 64*32 floats

    hipMemsetAsync(feat, 0, 64 * 32 * sizeof(float), stream);
    hipMemsetAsync(out + 64 * 64, 0, 64 * sizeof(float), stream);

    dim3 gridA(256 / TILE, 256 / TILE, 64);
    conv_feat_kernel<<<gridA, 256, 0, stream>>>(x, conv1_w, conv1_b, conv2_w,
                                                conv2_b, feat);
    router_gate_kernel<<<64, 64, 0, stream>>>(
        task_id, noise, mlp_w1, mlp_b1, mlp_w2, mlp_b2, deg_w, deg_b, keys,
        gate_w, gate_b, noise_w, noise_b, feat, out);
}

// Round 2
// 736.579 us; speedup vs baseline: 2.5257x; 2.5257x over previous
//
#include <hip/hip_runtime.h>
#include <math.h>

#define TILE 16

typedef __attribute__((ext_vector_type(8))) short short8;   // 8 bf16 in 4 VGPRs
typedef __attribute__((ext_vector_type(4))) float floatx4;  // MFMA acc

__device__ inline short bf16rne(float f) {
    unsigned u = __float_as_uint(f);
    unsigned r = (u + 0x7FFFu + ((u >> 16) & 1u)) >> 16;
    return (short)r;
}

// ---------------------------------------------------------------------------
// Kernel A: fused conv1+relu (MFMA via im2col) -> conv2+relu (MFMA via
// 9-shift implicit GEMM) -> spatial sum -> atomicAdd feat_sum[B][32].
// One block = (batch, 16x16 tile), 256 threads = 4 waves.
// ---------------------------------------------------------------------------
__global__ __launch_bounds__(256) void conv_feat_kernel(
    const float* __restrict__ x,      // (64,3,256,256)
    const float* __restrict__ w1,     // (16,3,3,3)  = [oc][27]
    const float* __restrict__ b1,     // (16,)
    const float* __restrict__ w2,     // (32,16,3,3) = [oc][ic][9]
    const float* __restrict__ b2,     // (32,)
    float* __restrict__ feat_sum)     // (64,32)
{
    __shared__ float s_in[3][20][20];     // input tile, halo 2 (4800 B)
    __shared__ short s_A[336][40];        // conv1 im2col, bf16, row pad 40 (26880 B)
    __shared__ short s_h1[324 * 24];      // conv1 out [pix][ic pad 24] bf16 (15552 B)
    __shared__ float s_part[4][32];

    const int t    = threadIdx.x;
    const int lane = t & 63, wv = t >> 6;
    const int q    = lane >> 4, ml = lane & 15;   // quad, lane-in-16
    const int tx = blockIdx.x, ty = blockIdx.y, b = blockIdx.z;

    // ---- stage input tile (halo 2), zero-padded at image border ----
    const int gy0 = ty * TILE - 2, gx0 = tx * TILE - 2;
    for (int i = t; i < 3 * 20 * 20; i += 256) {
        int c = i / 400, rem = i % 400, r = rem / 20, col = rem % 20;
        int gy = gy0 + r, gx = gx0 + col;
        float v = 0.0f;
        if ((unsigned)gy < 256u && (unsigned)gx < 256u)
            v = x[((b * 3 + c) * 256 + gy) * 256 + gx];
        s_in[c][r][col] = v;
    }
    // zero im2col pad rows 324..335 (k 0..31) so MFMA sees finite values
    for (int i = t; i < 12 * 16; i += 256) {
        int p = 324 + i / 16, kk = i % 16;
        ((unsigned*)&s_A[p][0])[kk] = 0u;
    }

    // ---- per-lane weight fragments (registers; no LDS weight traffic) ----
    // conv1 B-frag: B1[k = q*8+j][n = ml] = w1[ml*27 + k], zero for k>=27
    short8 B1;
#pragma unroll
    for (int j = 0; j < 8; ++j) {
        int k = q * 8 + j;
        B1[j] = (k < 27) ? bf16rne(w1[ml * 27 + k]) : (short)0;
    }
    float bias1 = b1[ml];

    // conv2 B-frags: kstep K pairs shifts (2K, 2K+1); K=4 pairs (8, zero).
    // k<16 -> shift 2K, ic=k ; k>=16 -> shift 2K+1, ic=k-16
    short8 B2[5][2];
    float bias2[2];
#pragma unroll
    for (int nt = 0; nt < 2; ++nt) {
        int oc = nt * 16 + ml;
        bias2[nt] = b2[oc];
#pragma unroll
        for (int K = 0; K < 5; ++K) {
#pragma unroll
            for (int j = 0; j < 8; ++j) {
                int k = q * 8 + j;
                int s = (k < 16) ? 2 * K : 2 * K + 1;
                int ic = k & 15;
                short v = 0;
                if (s < 9) v = bf16rne(w2[(oc * 16 + ic) * 9 + s]);
                B2[K][nt][j] = v;
            }
        }
    }
    __syncthreads();

    // ---- build conv1 im2col in bf16: A[p][k=c*9+ky*3+kx], k 27..31 = 0 ----
    for (int p = t; p < 324; p += 256) {
        int iy = p / 18, ix = p % 18;
        unsigned* dst = (unsigned*)&s_A[p][0];
#pragma unroll
        for (int i = 0; i < 16; ++i) {
            int k0 = 2 * i, k1 = 2 * i + 1;
            float f0 = (k0 < 27) ? s_in[k0 / 9][iy + (k0 % 9) / 3][ix + (k0 % 3)] : 0.0f;
            float f1 = (k1 < 27) ? s_in[k1 / 9][iy + (k1 % 9) / 3][ix + (k1 % 3)] : 0.0f;
            dst[i] = (unsigned)(unsigned short)bf16rne(f0) |
                     ((unsigned)(unsigned short)bf16rne(f1) << 16);
        }
    }
    __syncthreads();

    // ---- conv1 MFMA: 21 tiles of 16 pixels, one 16x16x32 each ----
    for (int tile = wv; tile < 21; tile += 4) {
        short8 A = *(const short8*)&s_A[tile * 16 + ml][q * 8];
        floatx4 acc = {0.f, 0.f, 0.f, 0.f};
        acc = __builtin_amdgcn_mfma_f32_16x16x32_bf16(A, B1, acc, 0, 0, 0);
#pragma unroll
        for (int r = 0; r < 4; ++r) {
            int p = tile * 16 + q * 4 + r;  // D: row = pixel, col = ml = oc
            if (p < 324) {
                int iy = p / 18, ix = p % 18;
                int gy = ty * TILE - 1 + iy, gx = tx * TILE - 1 + ix;
                float v = fmaxf(acc[r] + bias1, 0.0f);
                if (!((unsigned)gy < 256u && (unsigned)gx < 256u)) v = 0.0f;
                s_h1[p * 24 + ml] = bf16rne(v);
            }
        }
    }
    __syncthreads();

    // ---- conv2: wave handles rows oy = wv*4..wv*4+3; 2 oc-tiles; 5 ksteps --
    float persum0 = 0.f, persum1 = 0.f;
    for (int oy = wv * 4; oy < wv * 4 + 4; ++oy) {
        floatx4 acc0 = {0.f, 0.f, 0.f, 0.f}, acc1 = {0.f, 0.f, 0.f, 0.f};
#pragma unroll
        for (int K = 0; K < 5; ++K) {
            int s = (q < 2) ? 2 * K : 2 * K + 1;  // quad 0/1: shift 2K; 2/3: 2K+1
            short8 A;
            if (s < 9) {
                int ky = s / 3, kx = s % 3;
                int pix = (oy + ky) * 18 + (ml + kx);
                A = *(const short8*)&s_h1[pix * 24 + (q & 1) * 8];
            } else {
                A = short8{0, 0, 0, 0, 0, 0, 0, 0};  // B2 is zero for this half
            }
            acc0 = __builtin_amdgcn_mfma_f32_16x16x32_bf16(A, B2[K][0], acc0, 0, 0, 0);
            acc1 = __builtin_amdgcn_mfma_f32_16x16x32_bf16(A, B2[K][1], acc1, 0, 0, 0);
        }
#pragma unroll
        for (int r = 0; r < 4; ++r) {
            persum0 += fmaxf(acc0[r] + bias2[0], 0.0f);
            persum1 += fmaxf(acc1[r] + bias2[1], 0.0f);
        }
    }
    // sum over ox (spread across quads): xor-16 and xor-32 reduce
    persum0 += __shfl_xor(persum0, 16); persum0 += __shfl_xor(persum0, 32);
    persum1 += __shfl_xor(persum1, 16); persum1 += __shfl_xor(persum1, 32);
    if (lane < 16) { s_part[wv][ml] = persum0; s_part[wv][16 + ml] = persum1; }
    __syncthreads();
    if (t < 32) {
        float ssum = s_part[0][t] + s_part[1][t] + s_part[2][t] + s_part[3][t];
        atomicAdd(feat_sum + b * 32 + t, ssum);
    }
}

// ---------------------------------------------------------------------------
// Kernel B: gating. One block per batch row, 64 threads (= experts, 1 wave).
// ---------------------------------------------------------------------------
__global__ __launch_bounds__(64) void router_gate_kernel(
    const int* __restrict__ task_id,
    const float* __restrict__ noise,
    const float* __restrict__ mlp_w1,
    const float* __restrict__ mlp_b1,
    const float* __restrict__ mlp_w2,
    const float* __restrict__ mlp_b2,
    const float* __restrict__ deg_w,
    const float* __restrict__ deg_b,
    const float* __restrict__ keys,
    const float* __restrict__ gate_w,
    const float* __restrict__ gate_b,
    const float* __restrict__ noise_w,
    const float* __restrict__ noise_b,
    const float* __restrict__ feat_sum,
    float* __restrict__ out)
{
    const int b = blockIdx.x;
    const int e = threadIdx.x;

    __shared__ float s_te[32];
    __shared__ float s_comb[32];
    __shared__ float s_ew[64];

    if (e < 32) {
        float tf = (float)task_id[b];
        s_te[e] = fmaxf(tf * mlp_w1[e] + mlp_b1[e], 0.0f);
    }
    __syncthreads();
    if (e < 32) {
        float acc = mlp_b2[e];
        for (int k = 0; k < 32; ++k) acc += s_te[k] * mlp_w2[k * 32 + e];
        float dacc = deg_b[e];
        for (int c = 0; c < 32; ++c)
            dacc += (feat_sum[b * 32 + c] * (1.0f / 65536.0f)) * deg_w[c * 32 + e];
        s_comb[e] = acc + 0.2f * dacc;  // ALPHA = 0.8
    }
    __syncthreads();

    float s = 0.0f;
    for (int d = 0; d < 32; ++d) s += s_comb[d] * keys[e * 32 + d];
    s *= 0.17677669529663687f;  // 1/sqrt(32)

    float m = s;
    for (int off = 32; off; off >>= 1) m = fmaxf(m, __shfl_xor(m, off));
    float p = expf(s - m);
    float sum = p;
    for (int off = 32; off; off >>= 1) sum += __shfl_xor(sum, off);
    float w = p / sum;
    s_ew[e] = w;
    __syncthreads();

    float cl = gate_b[e], nz = noise_b[e];
    for (int k = 0; k < 64; ++k) {
        float ewk = s_ew[k];
        cl += ewk * gate_w[k * 64 + e];
        nz += ewk * noise_w[k * 64 + e];
    }
    float sp = (nz > 20.0f) ? nz : log1pf(expf(nz));
    float logit = cl + noise[b * 64 + e] * (sp + 0.01f);

    float v0 = logit; int i0 = e;
    for (int off = 32; off; off >>= 1) {
        float ov = __shfl_xor(v0, off);
        int   oi = __shfl_xor(i0, off);
        if (ov > v0 || (ov == v0 && oi < i0)) { v0 = ov; i0 = oi; }
    }
    float v1 = (e == i0) ? -INFINITY : logit; int i1 = e;
    for (int off = 32; off; off >>= 1) {
        float ov = __shfl_xor(v1, off);
        int   oi = __shfl_xor(i1, off);
        if (ov > v1 || (ov == v1 && oi < i1)) { v1 = ov; i1 = oi; }
    }

    float e1 = expf(v1 - v0);
    float g0 = 1.0f / (1.0f + e1);
    float g1 = e1 / (1.0f + e1);

    float g = (e == i0) ? g0 : (e == i1) ? g1 : 0.0f;
    out[b * 64 + e] = g;
    if (g != 0.0f) atomicAdd(out + 64 * 64 + e, g);
}

extern "C" void kernel_launch(void* const* d_in, const int* in_sizes, int n_in,
                              void* d_out, int out_size, void* d_ws, size_t ws_size,
                              hipStream_t stream) {
    const int*   task_id = (const int*)d_in[0];
    const float* x       = (const float*)d_in[1];
    const float* noise   = (const float*)d_in[2];
    const float* mlp_w1  = (const float*)d_in[3];
    const float* mlp_b1  = (const float*)d_in[4];
    const float* mlp_w2  = (const float*)d_in[5];
    const float* mlp_b2  = (const float*)d_in[6];
    const float* conv1_w = (const float*)d_in[7];
    const float* conv1_b = (const float*)d_in[8];
    const float* conv2_w = (const float*)d_in[9];
    const float* conv2_b = (const float*)d_in[10];
    const float* deg_w   = (const float*)d_in[11];
    const float* deg_b   = (const float*)d_in[12];
    const float* keys    = (const float*)d_in[13];
    const float* gate_w  = (const float*)d_in[14];
    const float* gate_b  = (const float*)d_in[15];
    const float* noise_w = (const float*)d_in[16];
    const float* noise_b = (const float*)d_in[17];

    float* out  = (float*)d_out;
    float* feat = (float*)d_ws;

    hipMemsetAsync(feat, 0, 64 * 32 * sizeof(float), stream);
    hipMemsetAsync(out + 64 * 64, 0, 64 * sizeof(float), stream);

    dim3 gridA(256 / TILE, 256 / TILE, 64);
    conv_feat_kernel<<<gridA, 256, 0, stream>>>(x, conv1_w, conv1_b, conv2_w,
                                                conv2_b, feat);
    router_gate_kernel<<<64, 64, 0, stream>>>(
        task_id, noise, mlp_w1, mlp_b1, mlp_w2, mlp_b2, deg_w, deg_b, keys,
        gate_w, gate_b, noise_w, noise_b, feat, out);
}

// Round 3
// 251.009 us; speedup vs baseline: 7.4116x; 2.9345x over previous
//
#include <hip/hip_runtime.h>
#include <math.h>

#define TILE 16

typedef __attribute__((ext_vector_type(8))) short short8;   // 8 bf16 in 4 VGPRs
typedef __attribute__((ext_vector_type(4))) float floatx4;  // MFMA acc

__device__ inline short bf16rne(float f) {
    unsigned u = __float_as_uint(f);
    unsigned r = (u + 0x7FFFu + ((u >> 16) & 1u)) >> 16;
    return (short)r;
}

// ws layout: [0, 8192)            feat_sum (64x32 f32)
//            [8192, 8192+11264)   frags: 11 x 64 x short8  (B1, B2[K][nt])
//            [+11264, +12288)     biases: 64 x float4 (bias1, bias2_0, bias2_1)
#define WS_FRAG_OFF 8192
#define WS_BIAS_OFF (8192 + 11 * 64 * 16)

// ---------------------------------------------------------------------------
// Setup kernel: build per-lane MFMA weight fragments once (1 block, 64 thr).
// ---------------------------------------------------------------------------
__global__ __launch_bounds__(64) void build_frags_kernel(
    const float* __restrict__ w1,   // (16,27)
    const float* __restrict__ b1,   // (16,)
    const float* __restrict__ w2,   // (32,16,9)
    const float* __restrict__ b2,   // (32,)
    void* __restrict__ ws)
{
    const int lane = threadIdx.x;
    const int q = lane >> 4, ml = lane & 15;
    short8* F = (short8*)((char*)ws + WS_FRAG_OFF);
    float*  Bv = (float*)((char*)ws + WS_BIAS_OFF);

    // B1[k = q*8+j][n = ml] = w1[ml*27 + k], zero for k>=27
    short8 B1;
#pragma unroll
    for (int j = 0; j < 8; ++j) {
        int k = q * 8 + j;
        B1[j] = (k < 27) ? bf16rne(w1[ml * 27 + k]) : (short)0;
    }
    F[0 * 64 + lane] = B1;

    // B2: k<16 -> shift 2K, ic=k ; k>=16 -> shift 2K+1, ic=k-16
#pragma unroll
    for (int nt = 0; nt < 2; ++nt) {
        int oc = nt * 16 + ml;
#pragma unroll
        for (int K = 0; K < 5; ++K) {
            short8 B;
#pragma unroll
            for (int j = 0; j < 8; ++j) {
                int k = q * 8 + j;
                int s = (k < 16) ? 2 * K : 2 * K + 1;
                int ic = k & 15;
                short v = 0;
                if (s < 9) v = bf16rne(w2[(oc * 16 + ic) * 9 + s]);
                B[j] = v;
            }
            F[(1 + K * 2 + nt) * 64 + lane] = B;
        }
    }
    Bv[lane * 4 + 0] = b1[ml];
    Bv[lane * 4 + 1] = b2[ml];
    Bv[lane * 4 + 2] = b2[16 + ml];
    Bv[lane * 4 + 3] = 0.0f;
}

// ---------------------------------------------------------------------------
// Kernel A: fused conv1+relu (direct-from-LDS MFMA) -> conv2+relu (9-shift
// implicit-GEMM MFMA) -> spatial sum -> atomicAdd feat_sum[B][32].
// One block = (batch, 16x16 tile), 256 threads = 4 waves. LDS ~21 KB.
// ---------------------------------------------------------------------------
__global__ __launch_bounds__(256, 5) void conv_feat_kernel(
    const float* __restrict__ x,      // (64,3,256,256)
    const void*  __restrict__ ws_ro,  // frags + biases
    float* __restrict__ feat_sum)     // (64,32)
{
    __shared__ float s_in[3][20][20];   // input tile, halo 2 (4800 B)
    __shared__ short s_h1[324 * 24];    // conv1 out [pix][ic pad24] bf16 (15552 B)
    __shared__ float s_part[4][32];

    const int t    = threadIdx.x;
    const int lane = t & 63, wv = t >> 6;
    const int q    = lane >> 4, ml = lane & 15;
    const int tx = blockIdx.x, ty = blockIdx.y, b = blockIdx.z;

    // ---- coalesced per-lane weight-fragment loads (precomputed) ----
    const short8* F = (const short8*)((const char*)ws_ro + WS_FRAG_OFF);
    const floatx4* Bv = (const floatx4*)((const char*)ws_ro + WS_BIAS_OFF);
    short8 B1 = F[0 * 64 + lane];
    short8 B2[5][2];
#pragma unroll
    for (int K = 0; K < 5; ++K) {
        B2[K][0] = F[(1 + K * 2 + 0) * 64 + lane];
        B2[K][1] = F[(1 + K * 2 + 1) * 64 + lane];
    }
    floatx4 bias = Bv[lane];   // .x=bias1  .y=bias2_0  .z=bias2_1

    // ---- stage input tile (halo 2), zero-padded at image border ----
    const int gy0 = ty * TILE - 2, gx0 = tx * TILE - 2;
    for (int i = t; i < 3 * 20 * 20; i += 256) {
        int c = i / 400, rem = i % 400, r = rem / 20, col = rem % 20;
        int gy = gy0 + r, gx = gx0 + col;
        float v = 0.0f;
        if ((unsigned)gy < 256u && (unsigned)gx < 256u)
            v = x[((b * 3 + c) * 256 + gy) * 256 + gx];
        s_in[c][r][col] = v;
    }
    __syncthreads();

    // ---- conv1: 21 MFMA tiles of 16 pixels; A-frag built from s_in ----
    for (int tile = wv; tile < 21; tile += 4) {
        int p = tile * 16 + ml;  // A row = pixel
        short8 A = short8{0, 0, 0, 0, 0, 0, 0, 0};
        if (p < 324) {
            int iy = p / 18, ix = p % 18;
#pragma unroll
            for (int j = 0; j < 8; ++j) {
                int k = q * 8 + j;
                float f = (k < 27) ? s_in[k / 9][iy + (k % 9) / 3][ix + (k % 3)] : 0.0f;
                A[j] = bf16rne(f);
            }
        }
        floatx4 acc = {0.f, 0.f, 0.f, 0.f};
        acc = __builtin_amdgcn_mfma_f32_16x16x32_bf16(A, B1, acc, 0, 0, 0);
#pragma unroll
        for (int r = 0; r < 4; ++r) {
            int p2 = tile * 16 + q * 4 + r;  // D: row = pixel, col = ml = oc
            if (p2 < 324) {
                int iy = p2 / 18, ix = p2 % 18;
                int gy = ty * TILE - 1 + iy, gx = tx * TILE - 1 + ix;
                float v = fmaxf(acc[r] + bias.x, 0.0f);
                if (!((unsigned)gy < 256u && (unsigned)gx < 256u)) v = 0.0f;
                s_h1[p2 * 24 + ml] = bf16rne(v);
            }
        }
    }
    __syncthreads();

    // ---- conv2: wave wv handles rows wv*4..wv*4+3; 2 oc-tiles; 5 ksteps ----
    float persum0 = 0.f, persum1 = 0.f;
    for (int oy = wv * 4; oy < wv * 4 + 4; ++oy) {
        floatx4 acc0 = {0.f, 0.f, 0.f, 0.f}, acc1 = {0.f, 0.f, 0.f, 0.f};
#pragma unroll
        for (int K = 0; K < 5; ++K) {
            int s = (q < 2) ? 2 * K : 2 * K + 1;  // quads 0/1: shift 2K; 2/3: 2K+1
            short8 A;
            if (s < 9) {
                int ky = s / 3, kx = s % 3;
                int pix = (oy + ky) * 18 + (ml + kx);
                A = *(const short8*)&s_h1[pix * 24 + (q & 1) * 8];
            } else {
                A = short8{0, 0, 0, 0, 0, 0, 0, 0};
            }
            acc0 = __builtin_amdgcn_mfma_f32_16x16x32_bf16(A, B2[K][0], acc0, 0, 0, 0);
            acc1 = __builtin_amdgcn_mfma_f32_16x16x32_bf16(A, B2[K][1], acc1, 0, 0, 0);
        }
#pragma unroll
        for (int r = 0; r < 4; ++r) {
            persum0 += fmaxf(acc0[r] + bias.y, 0.0f);
            persum1 += fmaxf(acc1[r] + bias.z, 0.0f);
        }
    }
    persum0 += __shfl_xor(persum0, 16); persum0 += __shfl_xor(persum0, 32);
    persum1 += __shfl_xor(persum1, 16); persum1 += __shfl_xor(persum1, 32);
    if (lane < 16) { s_part[wv][ml] = persum0; s_part[wv][16 + ml] = persum1; }
    __syncthreads();
    if (t < 32) {
        float ssum = s_part[0][t] + s_part[1][t] + s_part[2][t] + s_part[3][t];
        atomicAdd(feat_sum + b * 32 + t, ssum);
    }
}

// ---------------------------------------------------------------------------
// Kernel B: gating. One block per batch row, 64 threads (= experts, 1 wave).
// ---------------------------------------------------------------------------
__global__ __launch_bounds__(64) void router_gate_kernel(
    const int* __restrict__ task_id,
    const float* __restrict__ noise,
    const float* __restrict__ mlp_w1,
    const float* __restrict__ mlp_b1,
    const float* __restrict__ mlp_w2,
    const float* __restrict__ mlp_b2,
    const float* __restrict__ deg_w,
    const float* __restrict__ deg_b,
    const float* __restrict__ keys,
    const float* __restrict__ gate_w,
    const float* __restrict__ gate_b,
    const float* __restrict__ noise_w,
    const float* __restrict__ noise_b,
    const float* __restrict__ feat_sum,
    float* __restrict__ out)
{
    const int b = blockIdx.x;
    const int e = threadIdx.x;

    __shared__ float s_te[32];
    __shared__ float s_comb[32];
    __shared__ float s_ew[64];

    if (e < 32) {
        float tf = (float)task_id[b];
        s_te[e] = fmaxf(tf * mlp_w1[e] + mlp_b1[e], 0.0f);
    }
    __syncthreads();
    if (e < 32) {
        float acc = mlp_b2[e];
        for (int k = 0; k < 32; ++k) acc += s_te[k] * mlp_w2[k * 32 + e];
        float dacc = deg_b[e];
        for (int c = 0; c < 32; ++c)
            dacc += (feat_sum[b * 32 + c] * (1.0f / 65536.0f)) * deg_w[c * 32 + e];
        s_comb[e] = acc + 0.2f * dacc;  // ALPHA = 0.8
    }
    __syncthreads();

    float s = 0.0f;
    for (int d = 0; d < 32; ++d) s += s_comb[d] * keys[e * 32 + d];
    s *= 0.17677669529663687f;  // 1/sqrt(32)

    float m = s;
    for (int off = 32; off; off >>= 1) m = fmaxf(m, __shfl_xor(m, off));
    float p = expf(s - m);
    float sum = p;
    for (int off = 32; off; off >>= 1) sum += __shfl_xor(sum, off);
    float w = p / sum;
    s_ew[e] = w;
    __syncthreads();

    float cl = gate_b[e], nz = noise_b[e];
    for (int k = 0; k < 64; ++k) {
        float ewk = s_ew[k];
        cl += ewk * gate_w[k * 64 + e];
        nz += ewk * noise_w[k * 64 + e];
    }
    float sp = (nz > 20.0f) ? nz : log1pf(expf(nz));
    float logit = cl + noise[b * 64 + e] * (sp + 0.01f);

    float v0 = logit; int i0 = e;
    for (int off = 32; off; off >>= 1) {
        float ov = __shfl_xor(v0, off);
        int   oi = __shfl_xor(i0, off);
        if (ov > v0 || (ov == v0 && oi < i0)) { v0 = ov; i0 = oi; }
    }
    float v1 = (e == i0) ? -INFINITY : logit; int i1 = e;
    for (int off = 32; off; off >>= 1) {
        float ov = __shfl_xor(v1, off);
        int   oi = __shfl_xor(i1, off);
        if (ov > v1 || (ov == v1 && oi < i1)) { v1 = ov; i1 = oi; }
    }

    float e1 = expf(v1 - v0);
    float g0 = 1.0f / (1.0f + e1);
    float g1 = e1 / (1.0f + e1);

    float g = (e == i0) ? g0 : (e == i1) ? g1 : 0.0f;
    out[b * 64 + e] = g;
    if (g != 0.0f) atomicAdd(out + 64 * 64 + e, g);
}

extern "C" void kernel_launch(void* const* d_in, const int* in_sizes, int n_in,
                              void* d_out, int out_size, void* d_ws, size_t ws_size,
                              hipStream_t stream) {
    const int*   task_id = (const int*)d_in[0];
    const float* x       = (const float*)d_in[1];
    const float* noise   = (const float*)d_in[2];
    const float* mlp_w1  = (const float*)d_in[3];
    const float* mlp_b1  = (const float*)d_in[4];
    const float* mlp_w2  = (const float*)d_in[5];
    const float* mlp_b2  = (const float*)d_in[6];
    const float* conv1_w = (const float*)d_in[7];
    const float* conv1_b = (const float*)d_in[8];
    const float* conv2_w = (const float*)d_in[9];
    const float* conv2_b = (const float*)d_in[10];
    const float* deg_w   = (const float*)d_in[11];
    const float* deg_b   = (const float*)d_in[12];
    const float* keys    = (const float*)d_in[13];
    const float* gate_w  = (const float*)d_in[14];
    const float* gate_b  = (const float*)d_in[15];
    const float* noise_w = (const float*)d_in[16];
    const float* noise_b = (const float*)d_in[17];

    float* out  = (float*)d_out;
    float* feat = (float*)d_ws;

    hipMemsetAsync(feat, 0, 64 * 32 * sizeof(float), stream);
    hipMemsetAsync(out + 64 * 64, 0, 64 * sizeof(float), stream);

    build_frags_kernel<<<1, 64, 0, stream>>>(conv1_w, conv1_b, conv2_w,
                                             conv2_b, d_ws);
    dim3 gridA(256 / TILE, 256 / TILE, 64);
    conv_feat_kernel<<<gridA, 256, 0, stream>>>(x, d_ws, feat);
    router_gate_kernel<<<64, 64, 0, stream>>>(
        task_id, noise, mlp_w1, mlp_b1, mlp_w2, mlp_b2, deg_w, deg_b, keys,
        gate_w, gate_b, noise_w, noise_b, feat, out);
}

// Round 4
// 205.773 us; speedup vs baseline: 9.0409x; 1.2198x over previous
//
#include <hip/hip_runtime.h>
#include <math.h>

typedef __attribute__((ext_vector_type(8)))  short  short8;    // 8 bf16
typedef __attribute__((ext_vector_type(4)))  float  floatx4;
typedef __attribute__((ext_vector_type(16))) float  floatx16;
typedef __attribute__((ext_vector_type(2)))  float  floatx2;

__device__ inline short bf16rne(float f) {
    unsigned u = __float_as_uint(f);
    unsigned r = (u + 0x7FFFu + ((u >> 16) & 1u)) >> 16;
    return (short)r;
}
__device__ inline unsigned pack2bf(float a, float b) {
    return (unsigned)(unsigned short)bf16rne(a) |
           ((unsigned)(unsigned short)bf16rne(b) << 16);
}

// ws layout: [0,8192) feat_sum (64x32 f32); frags at 8192: 10 x 64 x short8
// (B1, B2[s=0..8]); biases at +10240: 64 x float2 {b1[lane&15], b2[lane&31]}
#define WS_FRAG_OFF 8192
#define WS_BIAS_OFF (8192 + 10 * 64 * 16)

// ---------------------------------------------------------------------------
// Setup: build MFMA weight fragments, zero feat_sum and out's load slots.
// ---------------------------------------------------------------------------
__global__ __launch_bounds__(256) void build_frags_kernel(
    const float* __restrict__ w1,   // (16,27)
    const float* __restrict__ b1,   // (16,)
    const float* __restrict__ w2,   // (32,16,9)
    const float* __restrict__ b2,   // (32,)
    void* __restrict__ ws,
    float* __restrict__ out)        // gates(4096) + load(64)
{
    const int t = threadIdx.x;
    float* feat = (float*)ws;
    for (int i = t; i < 2048; i += 256) feat[i] = 0.0f;
    if (t >= 64 && t < 128) out[4096 + (t - 64)] = 0.0f;

    if (t < 64) {
        const int lane = t;
        const int q = lane >> 4, ml = lane & 15;
        const int n32 = lane & 31, half = lane >> 5;
        short8* F = (short8*)((char*)ws + WS_FRAG_OFF);
        floatx2* Bv = (floatx2*)((char*)ws + WS_BIAS_OFF);

        // conv1 B-frag (16x16x32): B[k=q*8+j][n=ml] = w1[ml*27+k], 0 for k>=27
        short8 B1;
#pragma unroll
        for (int j = 0; j < 8; ++j) {
            int k = q * 8 + j;
            B1[j] = (k < 27) ? bf16rne(w1[ml * 27 + k]) : (short)0;
        }
        F[lane] = B1;

        // conv2 B-frags (32x32x16), one per shift s:
        // B[k = half*8+j = ic][n = n32 = oc] = w2[(oc*16+ic)*9 + s]
#pragma unroll
        for (int s = 0; s < 9; ++s) {
            short8 Bs;
#pragma unroll
            for (int j = 0; j < 8; ++j) {
                int ic = half * 8 + j;
                Bs[j] = bf16rne(w2[(n32 * 16 + ic) * 9 + s]);
            }
            F[(1 + s) * 64 + lane] = Bs;
        }
        floatx2 bb; bb.x = b1[ml]; bb.y = b2[n32];
        Bv[lane] = bb;
    }
}

// ---------------------------------------------------------------------------
// Kernel A: conv1+relu (16x16x32 MFMA) -> conv2+relu (32x32x16 MFMA, 9-shift
// implicit GEMM) -> spatial sum -> atomicAdd feat_sum[B][32].
// One block = (batch, 16x16 tile), 256 threads = 4 waves.
// ---------------------------------------------------------------------------
__global__ __launch_bounds__(256, 4) void conv_feat_kernel(
    const float* __restrict__ x,      // (64,3,256,256)
    const void*  __restrict__ ws_ro,
    float* __restrict__ feat_sum)     // (64,32)
{
    __shared__ short s_in[3 * 20 * 24];   // bf16 input tile [c][r][col pad24]
    __shared__ short s_h1[324 * 24];      // conv1 out [pix][ic pad24] bf16
    __shared__ float s_part[4][32];

    const int t    = threadIdx.x;
    const int lane = t & 63, wv = t >> 6;
    const int q    = lane >> 4, ml = lane & 15;
    const int n32  = lane & 31, half = lane >> 5;
    const int tx = blockIdx.x, ty = blockIdx.y, b = blockIdx.z;
    const bool border = (tx == 0) | (tx == 15) | (ty == 0) | (ty == 15);

    // ---- weight fragments (L2-hot, coalesced) ----
    const short8* F = (const short8*)((const char*)ws_ro + WS_FRAG_OFF);
    short8 B1 = F[lane];
    short8 B2[9];
#pragma unroll
    for (int s = 0; s < 9; ++s) B2[s] = F[(1 + s) * 64 + lane];
    floatx2 bias = ((const floatx2*)((const char*)ws_ro + WS_BIAS_OFF))[lane];

    // ---- conv1 A-gather lane-constant byte offsets (k = q*8+j = c*9+s) ----
    int lc[8];
#pragma unroll
    for (int j = 0; j < 8; ++j) {
        int k = q * 8 + j;
        int kk = (k < 27) ? k : 0;      // safe addr; value zeroed below
        int c = kk / 9, s = kk % 9;
        lc[j] = (c * 480 + (s / 3) * 24 + (s % 3)) * 2;
    }
    const bool q3 = (q == 3);

    // ---- stage input tile as bf16 (halo 2) ----
    const int gy0 = ty * 16 - 2, gx0 = tx * 16 - 2;
    const float* xb = x + (size_t)b * 3 * 65536;
    if (!border) {
        for (int i = t; i < 600; i += 256) {
            int c = i / 200, rem = i % 200, r = rem / 10, c2 = rem % 10;
            const float* p = xb + c * 65536 + (gy0 + r) * 256 + gx0 + 2 * c2;
            floatx2 v = *(const floatx2*)p;
            *(unsigned*)&s_in[(c * 20 + r) * 24 + 2 * c2] = pack2bf(v.x, v.y);
        }
    } else {
        for (int i = t; i < 600; i += 256) {
            int c = i / 200, rem = i % 200, r = rem / 10, c2 = rem % 10;
            int gy = gy0 + r, gx = gx0 + 2 * c2;
            float v0 = 0.0f, v1 = 0.0f;
            if ((unsigned)gy < 256u) {
                const float* p = xb + c * 65536 + gy * 256;
                if ((unsigned)gx < 256u)       v0 = p[gx];
                if ((unsigned)(gx + 1) < 256u) v1 = p[gx + 1];
            }
            *(unsigned*)&s_in[(c * 20 + r) * 24 + 2 * c2] = pack2bf(v0, v1);
        }
    }
    __syncthreads();

    // ---- conv1: 20 full tiles (no bounds checks) + tile 20 on wave 0 ----
#pragma unroll
    for (int i = 0; i < 5; ++i) {
        int tile = wv + 4 * i;          // 0..19, p = tile*16+ml <= 319 < 324
        int p = tile * 16 + ml;
        int iy = p / 18, ix = p % 18;
        int pixb = (iy * 24 + ix) * 2;
        short8 A;
#pragma unroll
        for (int j = 0; j < 8; ++j)
            A[j] = *(const short*)((const char*)s_in + pixb + lc[j]);
        if (q3) { A[3] = 0; A[4] = 0; A[5] = 0; A[6] = 0; A[7] = 0; }
        floatx4 acc = {0.f, 0.f, 0.f, 0.f};
        acc = __builtin_amdgcn_mfma_f32_16x16x32_bf16(A, B1, acc, 0, 0, 0);
        int p20 = tile * 16 + q * 4;    // D row = q*4+r, col = ml = oc
        int hb = p20 * 24 + ml;
        if (!border) {
#pragma unroll
            for (int r = 0; r < 4; ++r)
                s_h1[hb + r * 24] = bf16rne(fmaxf(acc[r] + bias.x, 0.0f));
        } else {
#pragma unroll
            for (int r = 0; r < 4; ++r) {
                int p2 = p20 + r;
                int iy2 = p2 / 18, ix2 = p2 % 18;
                int gy = ty * 16 - 1 + iy2, gx = tx * 16 - 1 + ix2;
                float v = fmaxf(acc[r] + bias.x, 0.0f);
                if (!((unsigned)gy < 256u && (unsigned)gx < 256u)) v = 0.0f;
                s_h1[hb + r * 24] = bf16rne(v);
            }
        }
    }
    if (wv == 0) {                      // tile 20: pixels 320..323
        int p = 320 + ml; if (p > 323) p = 323;   // clamp (rows >=4 unused)
        int iy = p / 18, ix = p % 18;
        int pixb = (iy * 24 + ix) * 2;
        short8 A;
#pragma unroll
        for (int j = 0; j < 8; ++j)
            A[j] = *(const short*)((const char*)s_in + pixb + lc[j]);
        if (q3) { A[3] = 0; A[4] = 0; A[5] = 0; A[6] = 0; A[7] = 0; }
        floatx4 acc = {0.f, 0.f, 0.f, 0.f};
        acc = __builtin_amdgcn_mfma_f32_16x16x32_bf16(A, B1, acc, 0, 0, 0);
        if (q == 0) {
#pragma unroll
            for (int r = 0; r < 4; ++r) {
                int p2 = 320 + r;       // < 324
                int iy2 = p2 / 18, ix2 = p2 % 18;
                int gy = ty * 16 - 1 + iy2, gx = tx * 16 - 1 + ix2;
                float v = fmaxf(acc[r] + bias.x, 0.0f);
                if (!((unsigned)gy < 256u && (unsigned)gx < 256u)) v = 0.0f;
                s_h1[p2 * 24 + ml] = bf16rne(v);
            }
        }
    }
    __syncthreads();

    // ---- conv2: 8 pixel-tiles of 32 (2 rows x 16 cols); wave does 2 ----
    // A[m = n32][k = half*8+j = ic]; B2[s] matches; D col = n32 = oc.
    float part = 0.0f;
#pragma unroll
    for (int tt = 0; tt < 2; ++tt) {
        int tl = 2 * wv + tt;                 // 0..7 -> out rows 2tl, 2tl+1
        int prow = 2 * tl + (n32 >> 4);       // pixel row in 16x16 out tile
        int pcol = n32 & 15;
        const short* base = &s_h1[(prow * 18 + pcol) * 24 + half * 8];
        floatx16 acc = {0.f,0.f,0.f,0.f,0.f,0.f,0.f,0.f,
                        0.f,0.f,0.f,0.f,0.f,0.f,0.f,0.f};
#pragma unroll
        for (int s = 0; s < 9; ++s) {
            int ky = s / 3, kx = s % 3;
            short8 A = *(const short8*)(base + (ky * 18 + kx) * 24);
            acc = __builtin_amdgcn_mfma_f32_32x32x16_bf16(A, B2[s], acc, 0, 0, 0);
        }
#pragma unroll
        for (int r = 0; r < 16; ++r) part += fmaxf(acc[r] + bias.y, 0.0f);
    }
    part += __shfl_xor(part, 32);             // sum the two k-halves' rows
    if (lane < 32) s_part[wv][n32] = part;
    __syncthreads();
    if (t < 32) {
        float ssum = s_part[0][t] + s_part[1][t] + s_part[2][t] + s_part[3][t];
        atomicAdd(feat_sum + b * 32 + t, ssum);
    }
}

// ---------------------------------------------------------------------------
// Kernel B: gating. One block per batch row, 64 threads (= experts, 1 wave).
// ---------------------------------------------------------------------------
__global__ __launch_bounds__(64) void router_gate_kernel(
    const int* __restrict__ task_id,
    const float* __restrict__ noise,
    const float* __restrict__ mlp_w1,
    const float* __restrict__ mlp_b1,
    const float* __restrict__ mlp_w2,
    const float* __restrict__ mlp_b2,
    const float* __restrict__ deg_w,
    const float* __restrict__ deg_b,
    const float* __restrict__ keys,
    const float* __restrict__ gate_w,
    const float* __restrict__ gate_b,
    const float* __restrict__ noise_w,
    const float* __restrict__ noise_b,
    const float* __restrict__ feat_sum,
    float* __restrict__ out)
{
    const int b = blockIdx.x;
    const int e = threadIdx.x;

    __shared__ float s_te[32];
    __shared__ float s_comb[32];
    __shared__ float s_ew[64];

    if (e < 32) {
        float tf = (float)task_id[b];
        s_te[e] = fmaxf(tf * mlp_w1[e] + mlp_b1[e], 0.0f);
    }
    __syncthreads();
    if (e < 32) {
        float acc = mlp_b2[e];
        for (int k = 0; k < 32; ++k) acc += s_te[k] * mlp_w2[k * 32 + e];
        float dacc = deg_b[e];
        for (int c = 0; c < 32; ++c)
            dacc += (feat_sum[b * 32 + c] * (1.0f / 65536.0f)) * deg_w[c * 32 + e];
        s_comb[e] = acc + 0.2f * dacc;  // ALPHA = 0.8
    }
    __syncthreads();

    float s = 0.0f;
    for (int d = 0; d < 32; ++d) s += s_comb[d] * keys[e * 32 + d];
    s *= 0.17677669529663687f;  // 1/sqrt(32)

    float m = s;
    for (int off = 32; off; off >>= 1) m = fmaxf(m, __shfl_xor(m, off));
    float p = expf(s - m);
    float sum = p;
    for (int off = 32; off; off >>= 1) sum += __shfl_xor(sum, off);
    float w = p / sum;
    s_ew[e] = w;
    __syncthreads();

    float cl = gate_b[e], nz = noise_b[e];
    for (int k = 0; k < 64; ++k) {
        float ewk = s_ew[k];
        cl += ewk * gate_w[k * 64 + e];
        nz += ewk * noise_w[k * 64 + e];
    }
    float sp = (nz > 20.0f) ? nz : log1pf(expf(nz));
    float logit = cl + noise[b * 64 + e] * (sp + 0.01f);

    float v0 = logit; int i0 = e;
    for (int off = 32; off; off >>= 1) {
        float ov = __shfl_xor(v0, off);
        int   oi = __shfl_xor(i0, off);
        if (ov > v0 || (ov == v0 && oi < i0)) { v0 = ov; i0 = oi; }
    }
    float v1 = (e == i0) ? -INFINITY : logit; int i1 = e;
    for (int off = 32; off; off >>= 1) {
        float ov = __shfl_xor(v1, off);
        int   oi = __shfl_xor(i1, off);
        if (ov > v1 || (ov == v1 && oi < i1)) { v1 = ov; i1 = oi; }
    }

    float e1 = expf(v1 - v0);
    float g0 = 1.0f / (1.0f + e1);
    float g1 = e1 / (1.0f + e1);

    float g = (e == i0) ? g0 : (e == i1) ? g1 : 0.0f;
    out[b * 64 + e] = g;
    if (g != 0.0f) atomicAdd(out + 64 * 64 + e, g);
}

extern "C" void kernel_launch(void* const* d_in, const int* in_sizes, int n_in,
                              void* d_out, int out_size, void* d_ws, size_t ws_size,
                              hipStream_t stream) {
    const int*   task_id = (const int*)d_in[0];
    const float* x       = (const float*)d_in[1];
    const float* noise   = (const float*)d_in[2];
    const float* mlp_w1  = (const float*)d_in[3];
    const float* mlp_b1  = (const float*)d_in[4];
    const float* mlp_w2  = (const float*)d_in[5];
    const float* mlp_b2  = (const float*)d_in[6];
    const float* conv1_w = (const float*)d_in[7];
    const float* conv1_b = (const float*)d_in[8];
    const float* conv2_w = (const float*)d_in[9];
    const float* conv2_b = (const float*)d_in[10];
    const float* deg_w   = (const float*)d_in[11];
    const float* deg_b   = (const float*)d_in[12];
    const float* keys    = (const float*)d_in[13];
    const float* gate_w  = (const float*)d_in[14];
    const float* gate_b  = (const float*)d_in[15];
    const float* noise_w = (const float*)d_in[16];
    const float* noise_b = (const float*)d_in[17];

    float* out  = (float*)d_out;
    float* feat = (float*)d_ws;

    build_frags_kernel<<<1, 256, 0, stream>>>(conv1_w, conv1_b, conv2_w,
                                              conv2_b, d_ws, out);
    dim3 gridA(16, 16, 64);
    conv_feat_kernel<<<gridA, 256, 0, stream>>>(x, d_ws, feat);
    router_gate_kernel<<<64, 64, 0, stream>>>(
        task_id, noise, mlp_w1, mlp_b1, mlp_w2, mlp_b2, deg_w, deg_b, keys,
        gate_w, gate_b, noise_w, noise_b, feat, out);
}

// Round 5
// 199.023 us; speedup vs baseline: 9.3476x; 1.0339x over previous
//
#include <hip/hip_runtime.h>
#include <math.h>

typedef __attribute__((ext_vector_type(8)))  short  short8;    // 8 bf16
typedef __attribute__((ext_vector_type(4)))  float  floatx4;
typedef __attribute__((ext_vector_type(16))) float  floatx16;
typedef __attribute__((ext_vector_type(2)))  float  floatx2;
typedef __attribute__((ext_vector_type(2)))  unsigned uintx2;

__device__ __forceinline__ short bf16rne(float f) {
    unsigned u = __float_as_uint(f);
    unsigned r = (u + 0x7FFFu + ((u >> 16) & 1u)) >> 16;
    return (short)r;
}

// pack two floats -> bf16x2 (one v_cvt_pk_bf16_f32 on gfx950)
__device__ __forceinline__ unsigned pk2(float a, float b) {
#if __has_builtin(__builtin_amdgcn_cvt_pk_bf16_f32)
    auto t = __builtin_amdgcn_cvt_pk_bf16_f32(a, b);
    unsigned u; __builtin_memcpy(&u, &t, 4); return u;
#else
    return (unsigned)(unsigned short)bf16rne(a) |
           ((unsigned)(unsigned short)bf16rne(b) << 16);
#endif
}

// ws layout: [0,8192) feat_sum; frags at 8192 (10 x 64 x 16B);
// conv1 C-init bias at +10240 (64 x float4); conv2 bias at +11264 (64 x f32)
#define WS_FRAG_OFF  8192
#define WS_BIAS1_OFF (WS_FRAG_OFF + 10 * 64 * 16)
#define WS_BIAS2_OFF (WS_BIAS1_OFF + 64 * 16)

// ---------------------------------------------------------------------------
// Setup: build MFMA weight fragments + bias tables, zero feat & out-load.
// ---------------------------------------------------------------------------
__global__ __launch_bounds__(256) void build_frags_kernel(
    const float* __restrict__ w1,   // (16,27)
    const float* __restrict__ b1,   // (16,)
    const float* __restrict__ w2,   // (32,16,9)
    const float* __restrict__ b2,   // (32,)
    void* __restrict__ ws,
    float* __restrict__ out)        // gates(4096) + load(64)
{
    const int t = threadIdx.x;
    float* feat = (float*)ws;
    for (int i = t; i < 2048; i += 256) feat[i] = 0.0f;
    if (t >= 64 && t < 128) out[4096 + (t - 64)] = 0.0f;

    if (t < 64) {
        const int lane = t;
        const int q = lane >> 4, ml = lane & 15;
        const int n32 = lane & 31, half = lane >> 5;
        short8* F = (short8*)((char*)ws + WS_FRAG_OFF);

        // conv1 W-as-A frag (16x16x32): A[m=ml=oc][k=q*8+j] = w1[ml*27+k]
        short8 W1;
#pragma unroll
        for (int j = 0; j < 8; ++j) {
            int k = q * 8 + j;
            W1[j] = (k < 27) ? bf16rne(w1[ml * 27 + k]) : (short)0;
        }
        F[lane] = W1;

        // conv2 B-frags (32x32x16), one per shift s:
        // B[k = half*8+j = ic][n = n32 = oc] = w2[(oc*16+ic)*9 + s]
#pragma unroll
        for (int s = 0; s < 9; ++s) {
            short8 Bs;
#pragma unroll
            for (int j = 0; j < 8; ++j) {
                int ic = half * 8 + j;
                Bs[j] = bf16rne(w2[(n32 * 16 + ic) * 9 + s]);
            }
            F[(1 + s) * 64 + lane] = Bs;
        }
        // conv1 C-init: lane holds rows oc = q*4+r
        floatx4 bv;
#pragma unroll
        for (int r = 0; r < 4; ++r) bv[r] = b1[q * 4 + r];
        ((floatx4*)((char*)ws + WS_BIAS1_OFF))[lane] = bv;
        ((float*)((char*)ws + WS_BIAS2_OFF))[lane] = b2[n32];
    }
}

// one conv1 MFMA micro-tile: gather B (16 pixels x K), mfma, relu, pack, b64 store
__device__ __forceinline__ void conv1_tile(
    short* __restrict__ s_h1, const short* __restrict__ s_in,
    const int* lcS, int gOff, int wIdx, bool valid, bool q3,
    short8 W1, floatx4 biasv)
{
    short8 Bx;
#pragma unroll
    for (int j = 0; j < 8; ++j) Bx[j] = s_in[gOff + lcS[j]];
    if (q3) { Bx[3] = 0; Bx[4] = 0; Bx[5] = 0; Bx[6] = 0; Bx[7] = 0; }
    floatx4 acc = biasv;
    acc = __builtin_amdgcn_mfma_f32_16x16x32_bf16(W1, Bx, acc, 0, 0, 0);
    float v0 = fmaxf(acc[0], 0.f), v1 = fmaxf(acc[1], 0.f);
    float v2 = fmaxf(acc[2], 0.f), v3 = fmaxf(acc[3], 0.f);
    if (!valid) { v0 = 0.f; v1 = 0.f; v2 = 0.f; v3 = 0.f; }
    uintx2 w; w.x = pk2(v0, v1); w.y = pk2(v2, v3);
    *(uintx2*)&s_h1[wIdx] = w;
}

// ---------------------------------------------------------------------------
// Kernel A: conv1+relu (16x16x32, W-as-A) -> conv2+relu (32x32x16, 9-shift)
// -> spatial sum -> atomicAdd feat_sum[B][32]. Block = (batch, 16x16 tile).
// ---------------------------------------------------------------------------
__global__ __launch_bounds__(256, 6) void conv_feat_kernel(
    const float* __restrict__ x,      // (64,3,256,256)
    const void*  __restrict__ ws_ro,
    float* __restrict__ feat_sum)     // (64,32)
{
    __shared__ short s_in[3 * 20 * 24];   // bf16 [c][r][col pad24]
    __shared__ short s_h1[324 * 24];      // [pix][16 ic, halves xor-swizzled by pix&1]
    __shared__ float s_part[4][32];

    const int t    = threadIdx.x;
    const int lane = t & 63, wv = t >> 6;
    const int q    = lane >> 4, ml = lane & 15;
    const int n32  = lane & 31, half = lane >> 5;
    const int tx = blockIdx.x, ty = blockIdx.y, b = blockIdx.z;
    const bool border = (tx == 0) | (tx == 15) | (ty == 0) | (ty == 15);

    // ---- weight fragments / biases (L2-hot, coalesced) ----
    const short8* F = (const short8*)((const char*)ws_ro + WS_FRAG_OFF);
    short8 W1 = F[lane];
    short8 B2[9];
#pragma unroll
    for (int s = 0; s < 9; ++s) B2[s] = F[(1 + s) * 64 + lane];
    floatx4 biasv = ((const floatx4*)((const char*)ws_ro + WS_BIAS1_OFF))[lane];
    float   b2v   = ((const float*)((const char*)ws_ro + WS_BIAS2_OFF))[lane];

    // conv1 gather lane-const offsets (shorts): k = q*8+j -> (c,ky,kx)
    int lcS[8];
#pragma unroll
    for (int j = 0; j < 8; ++j) {
        int k = q * 8 + j;
        int kk = (k < 27) ? k : 0;
        int c = kk / 9, s = kk % 9;
        lcS[j] = (c * 20 + s / 3) * 24 + (s % 3);
    }
    const bool q3 = (q == 3);
    const int swz1 = (q * 4) ^ ((ml & 1) * 8);   // conv1 write ic-position

    // ---- stage input tile as bf16 (halo 2) ----
    const int gy0 = ty * 16 - 2, gx0 = tx * 16 - 2;
    const float* xb = x + (size_t)b * 3 * 65536;
    if (!border) {
        for (int i = t; i < 600; i += 256) {
            int c = i / 200, rem = i % 200, r = rem / 10, c2 = rem % 10;
            const float* p = xb + c * 65536 + (gy0 + r) * 256 + gx0 + 2 * c2;
            floatx2 v = *(const floatx2*)p;
            *(unsigned*)&s_in[(c * 20 + r) * 24 + 2 * c2] = pk2(v.x, v.y);
        }
    } else {
        for (int i = t; i < 600; i += 256) {
            int c = i / 200, rem = i % 200, r = rem / 10, c2 = rem % 10;
            int gy = gy0 + r, gx = gx0 + 2 * c2;
            float v0 = 0.0f, v1 = 0.0f;
            if ((unsigned)gy < 256u) {
                const float* p = xb + c * 65536 + gy * 256;
                if ((unsigned)gx < 256u)       v0 = p[gx];
                if ((unsigned)(gx + 1) < 256u) v1 = p[gx + 1];
            }
            *(unsigned*)&s_in[(c * 20 + r) * 24 + 2 * c2] = pk2(v0, v1);
        }
    }
    __syncthreads();

    // ---- conv1: tiles 0..17 = (row=tile, cols 0..15); 18/19 = cols 16/17;
    //      corner = 4 px. D: row = oc = q*4+r, col = pixel = ml. ----
    if (!border) {
#pragma unroll
        for (int i = 0; i < 4; ++i) {
            int tile = wv + 4 * i;
            conv1_tile(s_h1, s_in, lcS, ml + tile * 24,
                       (tile * 18 + ml) * 24 + swz1, true, q3, W1, biasv);
        }
        int t4 = wv + 16;
        if (wv < 2) {
            conv1_tile(s_h1, s_in, lcS, ml + t4 * 24,
                       (t4 * 18 + ml) * 24 + swz1, true, q3, W1, biasv);
        } else {
            int cc = wv - 2;   // column 16+cc, rows = ml
            conv1_tile(s_h1, s_in, lcS, ml * 24 + 16 + cc,
                       (ml * 18 + 16 + cc) * 24 + ((q * 4) ^ (cc * 8)),
                       true, q3, W1, biasv);
        }
        if (wv == 0) {         // corner: (16,16),(16,17),(17,16),(17,17)
            int ml2 = ml & 3;
            int iy = 16 + (ml2 >> 1), ix = 16 + (ml2 & 1);
            conv1_tile(s_h1, s_in, lcS, iy * 24 + ix,
                       (iy * 18 + ix) * 24 + ((q * 4) ^ ((ml2 & 1) * 8)),
                       true, q3, W1, biasv);
        }
    } else {
        const bool gxOK = (unsigned)(tx * 16 - 1 + ml) < 256u;
#pragma unroll
        for (int i = 0; i < 4; ++i) {
            int tile = wv + 4 * i;
            bool rowOK = (unsigned)(ty * 16 - 1 + tile) < 256u;
            conv1_tile(s_h1, s_in, lcS, ml + tile * 24,
                       (tile * 18 + ml) * 24 + swz1, rowOK & gxOK, q3, W1, biasv);
        }
        int t4 = wv + 16;
        if (wv < 2) {
            bool rowOK = (unsigned)(ty * 16 - 1 + t4) < 256u;
            conv1_tile(s_h1, s_in, lcS, ml + t4 * 24,
                       (t4 * 18 + ml) * 24 + swz1, rowOK & gxOK, q3, W1, biasv);
        } else {
            int cc = wv - 2;
            bool ok = ((unsigned)(ty * 16 - 1 + ml) < 256u) &
                      ((unsigned)(tx * 16 + 15 + cc) < 256u);
            conv1_tile(s_h1, s_in, lcS, ml * 24 + 16 + cc,
                       (ml * 18 + 16 + cc) * 24 + ((q * 4) ^ (cc * 8)),
                       ok, q3, W1, biasv);
        }
        if (wv == 0) {
            int ml2 = ml & 3;
            int iy = 16 + (ml2 >> 1), ix = 16 + (ml2 & 1);
            bool ok = ((unsigned)(ty * 16 - 1 + iy) < 256u) &
                      ((unsigned)(tx * 16 - 1 + ix) < 256u);
            conv1_tile(s_h1, s_in, lcS, iy * 24 + ix,
                       (iy * 18 + ix) * 24 + ((q * 4) ^ ((ml2 & 1) * 8)),
                       ok, q3, W1, biasv);
        }
    }
    __syncthreads();

    // ---- conv2: 8 pixel-tiles of 32 (2 rows x 16 cols); wave does 2 ----
    float part = 0.0f;
    const int prow0 = (n32 >> 4), pcol = n32 & 15;
    const int sw  = (half * 8) ^ ((n32 & 1) * 8);   // even-kx half position
    const int swX = sw ^ 8;                         // odd-kx half position
#pragma unroll
    for (int tt = 0; tt < 2; ++tt) {
        int pix0 = (2 * (2 * wv + tt) + prow0) * 18 + pcol;
        const short* A0 = s_h1 + pix0 * 24 + sw;
        const short* A1 = s_h1 + pix0 * 24 + swX;
        floatx16 acc;
#pragma unroll
        for (int r = 0; r < 16; ++r) acc[r] = b2v;   // bias as C-init
#pragma unroll
        for (int s = 0; s < 9; ++s) {
            const int ky = s / 3, kx = s % 3;
            const short* p = ((kx & 1) ? A1 : A0) + (ky * 18 + kx) * 24;
            short8 Ax = *(const short8*)p;           // ds_read_b128, 16B aligned
            acc = __builtin_amdgcn_mfma_f32_32x32x16_bf16(Ax, B2[s], acc, 0, 0, 0);
        }
#pragma unroll
        for (int r = 0; r < 16; ++r) part += fmaxf(acc[r], 0.0f);
    }
    part += __shfl_xor(part, 32);
    if (lane < 32) s_part[wv][n32] = part;
    __syncthreads();
    if (t < 32) {
        float ssum = s_part[0][t] + s_part[1][t] + s_part[2][t] + s_part[3][t];
        atomicAdd(feat_sum + b * 32 + t, ssum);
    }
}

// ---------------------------------------------------------------------------
// Kernel B: gating. One block per batch row, 64 threads (= experts, 1 wave).
// ---------------------------------------------------------------------------
__global__ __launch_bounds__(64) void router_gate_kernel(
    const int* __restrict__ task_id,
    const float* __restrict__ noise,
    const float* __restrict__ mlp_w1,
    const float* __restrict__ mlp_b1,
    const float* __restrict__ mlp_w2,
    const float* __restrict__ mlp_b2,
    const float* __restrict__ deg_w,
    const float* __restrict__ deg_b,
    const float* __restrict__ keys,
    const float* __restrict__ gate_w,
    const float* __restrict__ gate_b,
    const float* __restrict__ noise_w,
    const float* __restrict__ noise_b,
    const float* __restrict__ feat_sum,
    float* __restrict__ out)
{
    const int b = blockIdx.x;
    const int e = threadIdx.x;

    __shared__ float s_te[32];
    __shared__ float s_comb[32];
    __shared__ float s_ew[64];

    if (e < 32) {
        float tf = (float)task_id[b];
        s_te[e] = fmaxf(tf * mlp_w1[e] + mlp_b1[e], 0.0f);
    }
    __syncthreads();
    if (e < 32) {
        float acc = mlp_b2[e];
        for (int k = 0; k < 32; ++k) acc += s_te[k] * mlp_w2[k * 32 + e];
        float dacc = deg_b[e];
        for (int c = 0; c < 32; ++c)
            dacc += (feat_sum[b * 32 + c] * (1.0f / 65536.0f)) * deg_w[c * 32 + e];
        s_comb[e] = acc + 0.2f * dacc;  // ALPHA = 0.8
    }
    __syncthreads();

    float s = 0.0f;
    for (int d = 0; d < 32; ++d) s += s_comb[d] * keys[e * 32 + d];
    s *= 0.17677669529663687f;  // 1/sqrt(32)

    float m = s;
    for (int off = 32; off; off >>= 1) m = fmaxf(m, __shfl_xor(m, off));
    float p = expf(s - m);
    float sum = p;
    for (int off = 32; off; off >>= 1) sum += __shfl_xor(sum, off);
    float w = p / sum;
    s_ew[e] = w;
    __syncthreads();

    float cl = gate_b[e], nz = noise_b[e];
    for (int k = 0; k < 64; ++k) {
        float ewk = s_ew[k];
        cl += ewk * gate_w[k * 64 + e];
        nz += ewk * noise_w[k * 64 + e];
    }
    float sp = (nz > 20.0f) ? nz : log1pf(expf(nz));
    float logit = cl + noise[b * 64 + e] * (sp + 0.01f);

    float v0 = logit; int i0 = e;
    for (int off = 32; off; off >>= 1) {
        float ov = __shfl_xor(v0, off);
        int   oi = __shfl_xor(i0, off);
        if (ov > v0 || (ov == v0 && oi < i0)) { v0 = ov; i0 = oi; }
    }
    float v1 = (e == i0) ? -INFINITY : logit; int i1 = e;
    for (int off = 32; off; off >>= 1) {
        float ov = __shfl_xor(v1, off);
        int   oi = __shfl_xor(i1, off);
        if (ov > v1 || (ov == v1 && oi < i1)) { v1 = ov; i1 = oi; }
    }

    float e1 = expf(v1 - v0);
    float g0 = 1.0f / (1.0f + e1);
    float g1 = e1 / (1.0f + e1);

    float g = (e == i0) ? g0 : (e == i1) ? g1 : 0.0f;
    out[b * 64 + e] = g;
    if (g != 0.0f) atomicAdd(out + 64 * 64 + e, g);
}

extern "C" void kernel_launch(void* const* d_in, const int* in_sizes, int n_in,
                              void* d_out, int out_size, void* d_ws, size_t ws_size,
                              hipStream_t stream) {
    const int*   task_id = (const int*)d_in[0];
    const float* x       = (const float*)d_in[1];
    const float* noise   = (const float*)d_in[2];
    const float* mlp_w1  = (const float*)d_in[3];
    const float* mlp_b1  = (const float*)d_in[4];
    const float* mlp_w2  = (const float*)d_in[5];
    const float* mlp_b2  = (const float*)d_in[6];
    const float* conv1_w = (const float*)d_in[7];
    const float* conv1_b = (const float*)d_in[8];
    const float* conv2_w = (const float*)d_in[9];
    const float* conv2_b = (const float*)d_in[10];
    const float* deg_w   = (const float*)d_in[11];
    const float* deg_b   = (const float*)d_in[12];
    const float* keys    = (const float*)d_in[13];
    const float* gate_w  = (const float*)d_in[14];
    const float* gate_b  = (const float*)d_in[15];
    const float* noise_w = (const float*)d_in[16];
    const float* noise_b = (const float*)d_in[17];

    float* out  = (float*)d_out;
    float* feat = (float*)d_ws;

    build_frags_kernel<<<1, 256, 0, stream>>>(conv1_w, conv1_b, conv2_w,
                                              conv2_b, d_ws, out);
    dim3 gridA(16, 16, 64);
    conv_feat_kernel<<<gridA, 256, 0, stream>>>(x, d_ws, feat);
    router_gate_kernel<<<64, 64, 0, stream>>>(
        task_id, noise, mlp_w1, mlp_b1, mlp_w2, mlp_b2, deg_w, deg_b, keys,
        gate_w, gate_b, noise_w, noise_b, feat, out);
}

// Round 7
// 182.722 us; speedup vs baseline: 10.1814x; 1.0892x over previous
//
#include <hip/hip_runtime.h>
#include <math.h>

typedef __attribute__((ext_vector_type(8)))  short  short8;    // 8 bf16
typedef __attribute__((ext_vector_type(4)))  short  svec4;     // 4 bf16 (b64)
typedef __attribute__((ext_vector_type(4)))  float  floatx4;
typedef __attribute__((ext_vector_type(16))) float  floatx16;
typedef __attribute__((ext_vector_type(2)))  unsigned uintx2;

__device__ __forceinline__ short bf16rne(float f) {
    unsigned u = __float_as_uint(f);
    unsigned r = (u + 0x7FFFu + ((u >> 16) & 1u)) >> 16;
    return (short)r;
}
__device__ __forceinline__ unsigned pk2(float a, float b) {
#if __has_builtin(__builtin_amdgcn_cvt_pk_bf16_f32)
    auto t = __builtin_amdgcn_cvt_pk_bf16_f32(a, b);
    unsigned u; __builtin_memcpy(&u, &t, 4); return u;
#else
    return (unsigned)(unsigned short)bf16rne(a) |
           ((unsigned)(unsigned short)bf16rne(b) << 16);
#endif
}

// ws: [0,8192) feat_sum; frags at 8192: 11 x 64 x 16B (W1a, W1b, B2[0..8]);
// conv1 C-init bias at +11264 (64 x float4); conv2 bias at +12288 (64 x f32)
#define WS_FRAG_OFF  8192
#define WS_BIAS1_OFF (WS_FRAG_OFF + 11 * 64 * 16)
#define WS_BIAS2_OFF (WS_BIAS1_OFF + 64 * 16)

// ---------------------------------------------------------------------------
// Setup: build MFMA weight fragments + bias tables, zero feat & out-load.
// conv1 K-map: k = p*4 + c for positions p=0..7 (MFMA #1); position 8 in
// MFMA #2 at k=c (rest zero). c=3 is a zero pad channel.
// ---------------------------------------------------------------------------
__global__ __launch_bounds__(256) void build_frags_kernel(
    const float* __restrict__ w1,   // (16,3,9) = [oc][c][p]
    const float* __restrict__ b1,   // (16,)
    const float* __restrict__ w2,   // (32,16,9)
    const float* __restrict__ b2,   // (32,)
    void* __restrict__ ws,
    float* __restrict__ out)        // gates(4096) + load(64)
{
    const int t = threadIdx.x;
    float* feat = (float*)ws;
    for (int i = t; i < 2048; i += 256) feat[i] = 0.0f;
    if (t >= 64 && t < 128) out[4096 + (t - 64)] = 0.0f;

    if (t < 64) {
        const int lane = t;
        const int q = lane >> 4, ml = lane & 15;
        const int n32 = lane & 31, half = lane >> 5;
        short8* F = (short8*)((char*)ws + WS_FRAG_OFF);

        // W1a (A-operand, 16x16x32): A[m=ml=oc][k=q*8+j], p=q*2+(j>>2), c=j&3
        short8 W1a;
#pragma unroll
        for (int j = 0; j < 8; ++j) {
            int p = q * 2 + (j >> 2), c = j & 3;
            W1a[j] = (c < 3) ? bf16rne(w1[ml * 27 + c * 9 + p]) : (short)0;
        }
        F[0 * 64 + lane] = W1a;

        // W1b: position 8 only, k=c (q==0, j<3); zero elsewhere
        short8 W1b;
#pragma unroll
        for (int j = 0; j < 8; ++j) {
            W1b[j] = (q == 0 && j < 3) ? bf16rne(w1[ml * 27 + j * 9 + 8])
                                       : (short)0;
        }
        F[1 * 64 + lane] = W1b;

        // conv2 B-frags (32x32x16): B[k=half*8+j=ic][n=n32=oc] = w2[(oc*16+ic)*9+s]
#pragma unroll
        for (int s = 0; s < 9; ++s) {
            short8 Bs;
#pragma unroll
            for (int j = 0; j < 8; ++j) {
                int ic = half * 8 + j;
                Bs[j] = bf16rne(w2[(n32 * 16 + ic) * 9 + s]);
            }
            F[(2 + s) * 64 + lane] = Bs;
        }
        floatx4 bv;
#pragma unroll
        for (int r = 0; r < 4; ++r) bv[r] = b1[q * 4 + r];
        ((floatx4*)((char*)ws + WS_BIAS1_OFF))[lane] = bv;
        ((float*)((char*)ws + WS_BIAS2_OFF))[lane] = b2[n32];
    }
}

// one conv1 micro-tile: 3 x ds_read_b64 gather, 2 MFMA, relu, pack, b64 store
__device__ __forceinline__ void conv1_tile(
    short* __restrict__ s_h1, const short* __restrict__ s_in4,
    const int* lcB, int basePixByte, int wIdx, bool valid, bool wmask,
    short8 W1a, short8 W1b, floatx4 biasv)
{
    const char* base = (const char*)s_in4 + basePixByte;
    svec4 r0 = *(const svec4*)(base + lcB[0]);
    svec4 r1 = *(const svec4*)(base + lcB[1]);
    svec4 r2 = *(const svec4*)(base + lcB[2]);
    short8 Bx, By;
    Bx[0]=r0[0]; Bx[1]=r0[1]; Bx[2]=r0[2]; Bx[3]=r0[3];
    Bx[4]=r1[0]; Bx[5]=r1[1]; Bx[6]=r1[2]; Bx[7]=r1[3];
    By[0]=r2[0]; By[1]=r2[1]; By[2]=r2[2]; By[3]=r2[3];
    By[4]=r2[0]; By[5]=r2[1]; By[6]=r2[2]; By[7]=r2[3];   // W1b=0 for k>=4
    floatx4 acc = biasv;
    acc = __builtin_amdgcn_mfma_f32_16x16x32_bf16(W1a, Bx, acc, 0, 0, 0);
    acc = __builtin_amdgcn_mfma_f32_16x16x32_bf16(W1b, By, acc, 0, 0, 0);
    float v0 = fmaxf(acc[0], 0.f), v1 = fmaxf(acc[1], 0.f);
    float v2 = fmaxf(acc[2], 0.f), v3 = fmaxf(acc[3], 0.f);
    if (!valid) { v0 = 0.f; v1 = 0.f; v2 = 0.f; v3 = 0.f; }
    if (wmask) {
        uintx2 w; w.x = pk2(v0, v1); w.y = pk2(v2, v3);
        *(uintx2*)&s_h1[wIdx] = w;
    }
}

// ---------------------------------------------------------------------------
// Kernel A: conv1+relu (2x 16x16x32 MFMA, b64 gather) -> conv2+relu
// (32x32x16 MFMA, 9-shift) -> spatial sum -> atomicAdd feat_sum[B][32].
// ---------------------------------------------------------------------------
__global__ __launch_bounds__(256, 6) void conv_feat_kernel(
    const float* __restrict__ x,      // (64,3,256,256)
    const void*  __restrict__ ws_ro,
    float* __restrict__ feat_sum)     // (64,32)
{
    __shared__ short s_in4[20 * 20 * 4];  // bf16 [r][col][c pad4] (3200 B)
    __shared__ short s_h1[324 * 24];      // [pix][16 ic @ +0, pad to 24]
    __shared__ float s_part[4][32];

    const int t    = threadIdx.x;
    const int lane = t & 63, wv = t >> 6;
    const int q    = lane >> 4, ml = lane & 15;
    const int n32  = lane & 31, half = lane >> 5;
    const int tx = blockIdx.x, ty = blockIdx.y, b = blockIdx.z;
    const bool border = (tx == 0) | (tx == 15) | (ty == 0) | (ty == 15);

    // ---- weight fragments / biases ----
    const short8* F = (const short8*)((const char*)ws_ro + WS_FRAG_OFF);
    short8 W1a = F[0 * 64 + lane];
    short8 W1b = F[1 * 64 + lane];
    short8 B2[9];
#pragma unroll
    for (int s = 0; s < 9; ++s) B2[s] = F[(2 + s) * 64 + lane];
    floatx4 biasv = ((const floatx4*)((const char*)ws_ro + WS_BIAS1_OFF))[lane];
    float   b2v   = ((const float*)((const char*)ws_ro + WS_BIAS2_OFF))[lane];

    // conv1 gather byte offsets: positions q*2, q*2+1, 8
    int lcB[3];
    {
        int p0 = q * 2, p1 = q * 2 + 1;
        lcB[0] = ((p0 / 3) * 20 + p0 % 3) * 8;
        lcB[1] = ((p1 / 3) * 20 + p1 % 3) * 8;
        lcB[2] = (2 * 20 + 2) * 8;
    }

    // ---- stage input tile as bf16 [r][col][4] (halo 2, pad c=3 -> 0) ----
    const int gy0 = ty * 16 - 2, gx0 = tx * 16 - 2;
    const float* xb = x + (size_t)b * 3 * 65536;
    if (!border) {
        for (int i = t; i < 400; i += 256) {
            int r = i / 20, col = i % 20;
            const float* p = xb + (gy0 + r) * 256 + (gx0 + col);
            float v0 = p[0], v1 = p[65536], v2 = p[131072];
            uintx2 w; w.x = pk2(v0, v1); w.y = pk2(v2, 0.f);
            *(uintx2*)&s_in4[i * 4] = w;
        }
    } else {
        for (int i = t; i < 400; i += 256) {
            int r = i / 20, col = i % 20;
            int gy = gy0 + r, gx = gx0 + col;
            float v0 = 0.f, v1 = 0.f, v2 = 0.f;
            if ((unsigned)gy < 256u && (unsigned)gx < 256u) {
                const float* p = xb + gy * 256 + gx;
                v0 = p[0]; v1 = p[65536]; v2 = p[131072];
            }
            uintx2 w; w.x = pk2(v0, v1); w.y = pk2(v2, 0.f);
            *(uintx2*)&s_in4[i * 4] = w;
        }
    }
    __syncthreads();

    // ---- conv1 over 18x18 h1 region: 18 row-tiles + 2 col-tiles + corner ----
    const int mlb = ml * 8;            // pixel byte step within a row-tile
    const int wbase = ml * 24 + q * 4; // h1 write base (shorts)
    if (!border) {
#pragma unroll
        for (int i = 0; i < 4; ++i) {
            int tile = wv + 4 * i;
            conv1_tile(s_h1, s_in4, lcB, tile * 160 + mlb,
                       tile * 432 + wbase, true, true, W1a, W1b, biasv);
        }
        if (wv < 2) {
            int tile = wv + 16;
            conv1_tile(s_h1, s_in4, lcB, tile * 160 + mlb,
                       tile * 432 + wbase, true, true, W1a, W1b, biasv);
        } else {
            int cc = wv - 2;           // column 16+cc, rows = ml
            conv1_tile(s_h1, s_in4, lcB, ml * 160 + (16 + cc) * 8,
                       (ml * 18 + 16 + cc) * 24 + q * 4, true, true,
                       W1a, W1b, biasv);
        }
        if (wv == 0) {                 // corner 4 px
            int ml2 = ml & 3;
            int iy = 16 + (ml2 >> 1), ix = 16 + (ml2 & 1);
            conv1_tile(s_h1, s_in4, lcB, iy * 160 + ix * 8,
                       (iy * 18 + ix) * 24 + q * 4, true, ml < 4,
                       W1a, W1b, biasv);
        }
    } else {
        const bool gxOK = (unsigned)(tx * 16 - 1 + ml) < 256u;
#pragma unroll
        for (int i = 0; i < 4; ++i) {
            int tile = wv + 4 * i;
            bool ok = ((unsigned)(ty * 16 - 1 + tile) < 256u) & gxOK;
            conv1_tile(s_h1, s_in4, lcB, tile * 160 + mlb,
                       tile * 432 + wbase, ok, true, W1a, W1b, biasv);
        }
        if (wv < 2) {
            int tile = wv + 16;
            bool ok = ((unsigned)(ty * 16 - 1 + tile) < 256u) & gxOK;
            conv1_tile(s_h1, s_in4, lcB, tile * 160 + mlb,
                       tile * 432 + wbase, ok, true, W1a, W1b, biasv);
        } else {
            int cc = wv - 2;
            bool ok = ((unsigned)(ty * 16 - 1 + ml) < 256u) &
                      ((unsigned)(tx * 16 + 15 + cc) < 256u);
            conv1_tile(s_h1, s_in4, lcB, ml * 160 + (16 + cc) * 8,
                       (ml * 18 + 16 + cc) * 24 + q * 4, ok, true,
                       W1a, W1b, biasv);
        }
        if (wv == 0) {
            int ml2 = ml & 3;
            int iy = 16 + (ml2 >> 1), ix = 16 + (ml2 & 1);
            bool ok = ((unsigned)(ty * 16 - 1 + iy) < 256u) &
                      ((unsigned)(tx * 16 - 1 + ix) < 256u);
            conv1_tile(s_h1, s_in4, lcB, iy * 160 + ix * 8,
                       (iy * 18 + ix) * 24 + q * 4, ok, ml < 4,
                       W1a, W1b, biasv);
        }
    }
    __syncthreads();

    // ---- conv2: 8 pixel-tiles of 32 (2 rows x 16 cols); wave does 2 ----
    float part = 0.0f;
    const int prow0 = (n32 >> 4), pcol = n32 & 15;
#pragma unroll
    for (int tt = 0; tt < 2; ++tt) {
        int pix0 = (2 * (2 * wv + tt) + prow0) * 18 + pcol;
        const short* A0 = s_h1 + pix0 * 24 + half * 8;
        floatx16 acc;
#pragma unroll
        for (int r = 0; r < 16; ++r) acc[r] = b2v;
#pragma unroll
        for (int s = 0; s < 9; ++s) {
            const int ky = s / 3, kx = s % 3;
            short8 Ax = *(const short8*)(A0 + (ky * 18 + kx) * 24);
            acc = __builtin_amdgcn_mfma_f32_32x32x16_bf16(Ax, B2[s], acc, 0, 0, 0);
        }
#pragma unroll
        for (int r = 0; r < 16; ++r) part += fmaxf(acc[r], 0.0f);
    }
    part += __shfl_xor(part, 32);
    if (lane < 32) s_part[wv][n32] = part;
    __syncthreads();
    if (t < 32) {
        float ssum = s_part[0][t] + s_part[1][t] + s_part[2][t] + s_part[3][t];
        atomicAdd(feat_sum + b * 32 + t, ssum);
    }
}

// ---------------------------------------------------------------------------
// Kernel B: gating. One block per batch row, 64 threads (= experts, 1 wave).
// ---------------------------------------------------------------------------
__global__ __launch_bounds__(64) void router_gate_kernel(
    const int* __restrict__ task_id,
    const float* __restrict__ noise,
    const float* __restrict__ mlp_w1,
    const float* __restrict__ mlp_b1,
    const float* __restrict__ mlp_w2,
    const float* __restrict__ mlp_b2,
    const float* __restrict__ deg_w,
    const float* __restrict__ deg_b,
    const float* __restrict__ keys,
    const float* __restrict__ gate_w,
    const float* __restrict__ gate_b,
    const float* __restrict__ noise_w,
    const float* __restrict__ noise_b,
    const float* __restrict__ feat_sum,
    float* __restrict__ out)
{
    const int b = blockIdx.x;
    const int e = threadIdx.x;

    __shared__ float s_te[32];
    __shared__ float s_comb[32];
    __shared__ float s_ew[64];

    if (e < 32) {
        float tf = (float)task_id[b];
        s_te[e] = fmaxf(tf * mlp_w1[e] + mlp_b1[e], 0.0f);
    }
    __syncthreads();
    if (e < 32) {
        float acc = mlp_b2[e];
        for (int k = 0; k < 32; ++k) acc += s_te[k] * mlp_w2[k * 32 + e];
        float dacc = deg_b[e];
        for (int c = 0; c < 32; ++c)
            dacc += (feat_sum[b * 32 + c] * (1.0f / 65536.0f)) * deg_w[c * 32 + e];
        s_comb[e] = acc + 0.2f * dacc;  // ALPHA = 0.8
    }
    __syncthreads();

    float s = 0.0f;
    for (int d = 0; d < 32; ++d) s += s_comb[d] * keys[e * 32 + d];
    s *= 0.17677669529663687f;  // 1/sqrt(32)

    float m = s;
    for (int off = 32; off; off >>= 1) m = fmaxf(m, __shfl_xor(m, off));
    float p = expf(s - m);
    float sum = p;
    for (int off = 32; off; off >>= 1) sum += __shfl_xor(sum, off);
    float w = p / sum;
    s_ew[e] = w;
    __syncthreads();

    float cl = gate_b[e], nz = noise_b[e];
    for (int k = 0; k < 64; ++k) {
        float ewk = s_ew[k];
        cl += ewk * gate_w[k * 64 + e];
        nz += ewk * noise_w[k * 64 + e];
    }
    float sp = (nz > 20.0f) ? nz : log1pf(expf(nz));
    float logit = cl + noise[b * 64 + e] * (sp + 0.01f);

    float v0 = logit; int i0 = e;
    for (int off = 32; off; off >>= 1) {
        float ov = __shfl_xor(v0, off);
        int   oi = __shfl_xor(i0, off);
        if (ov > v0 || (ov == v0 && oi < i0)) { v0 = ov; i0 = oi; }
    }
    float v1 = (e == i0) ? -INFINITY : logit; int i1 = e;
    for (int off = 32; off; off >>= 1) {
        float ov = __shfl_xor(v1, off);
        int   oi = __shfl_xor(i1, off);
        if (ov > v1 || (ov == v1 && oi < i1)) { v1 = ov; i1 = oi; }
    }

    float e1 = expf(v1 - v0);
    float g0 = 1.0f / (1.0f + e1);
    float g1 = e1 / (1.0f + e1);

    float g = (e == i0) ? g0 : (e == i1) ? g1 : 0.0f;
    out[b * 64 + e] = g;
    if (g != 0.0f) atomicAdd(out + 64 * 64 + e, g);
}

extern "C" void kernel_launch(void* const* d_in, const int* in_sizes, int n_in,
                              void* d_out, int out_size, void* d_ws, size_t ws_size,
                              hipStream_t stream) {
    const int*   task_id = (const int*)d_in[0];
    const float* x       = (const float*)d_in[1];
    const float* noise   = (const float*)d_in[2];
    const float* mlp_w1  = (const float*)d_in[3];
    const float* mlp_b1  = (const float*)d_in[4];
    const float* mlp_w2  = (const float*)d_in[5];
    const float* mlp_b2  = (const float*)d_in[6];
    const float* conv1_w = (const float*)d_in[7];
    const float* conv1_b = (const float*)d_in[8];
    const float* conv2_w = (const float*)d_in[9];
    const float* conv2_b = (const float*)d_in[10];
    const float* deg_w   = (const float*)d_in[11];
    const float* deg_b   = (const float*)d_in[12];
    const float* keys    = (const float*)d_in[13];
    const float* gate_w  = (const float*)d_in[14];
    const float* gate_b  = (const float*)d_in[15];
    const float* noise_w = (const float*)d_in[16];
    const float* noise_b = (const float*)d_in[17];

    float* out  = (float*)d_out;
    float* feat = (float*)d_ws;

    build_frags_kernel<<<1, 256, 0, stream>>>(conv1_w, conv1_b, conv2_w,
                                              conv2_b, d_ws, out);
    dim3 gridA(16, 16, 64);
    conv_feat_kernel<<<gridA, 256, 0, stream>>>(x, d_ws, feat);
    router_gate_kernel<<<64, 64, 0, stream>>>(
        task_id, noise, mlp_w1, mlp_b1, mlp_w2, mlp_b2, deg_w, deg_b, keys,
        gate_w, gate_b, noise_w, noise_b, feat, out);
}

// Round 8
// 174.095 us; speedup vs baseline: 10.6860x; 1.0496x over previous
//
#include <hip/hip_runtime.h>
#include <math.h>

typedef __attribute__((ext_vector_type(8)))  short  short8;    // 8 bf16
typedef __attribute__((ext_vector_type(4)))  short  svec4;     // 4 bf16 (b64)
typedef __attribute__((ext_vector_type(4)))  float  floatx4;
typedef __attribute__((ext_vector_type(16))) float  floatx16;
typedef __attribute__((ext_vector_type(2)))  unsigned uintx2;

__device__ __forceinline__ short bf16rne(float f) {
    unsigned u = __float_as_uint(f);
    unsigned r = (u + 0x7FFFu + ((u >> 16) & 1u)) >> 16;
    return (short)r;
}
__device__ __forceinline__ unsigned pk2(float a, float b) {
#if __has_builtin(__builtin_amdgcn_cvt_pk_bf16_f32)
    auto t = __builtin_amdgcn_cvt_pk_bf16_f32(a, b);
    unsigned u; __builtin_memcpy(&u, &t, 4); return u;
#else
    return (unsigned)(unsigned short)bf16rne(a) |
           ((unsigned)(unsigned short)bf16rne(b) << 16);
#endif
}

// ws: [0,8192) feat_sum; frags at 8192: 11 x 64 x 16B (W1a, W1b, B2[0..8]);
// conv1 C-init bias at +11264 (64 x float4); conv2 bias at +12288 (64 x f32)
#define WS_FRAG_OFF  8192
#define WS_BIAS1_OFF (WS_FRAG_OFF + 11 * 64 * 16)
#define WS_BIAS2_OFF (WS_BIAS1_OFF + 64 * 16)

#define PLANE_B 18496            // bytes per h1 ic-half plane (34*34*16)

// ---------------------------------------------------------------------------
// Setup: build MFMA weight fragments + bias tables, zero feat & out-load.
// conv1 K-map: k = p*4 + c for positions p=0..7 (MFMA #1); position 8 in
// MFMA #2 at k=c (rest zero). c=3 is a zero pad channel.
// ---------------------------------------------------------------------------
__global__ __launch_bounds__(256) void build_frags_kernel(
    const float* __restrict__ w1,   // (16,3,9) = [oc][c][p]
    const float* __restrict__ b1,   // (16,)
    const float* __restrict__ w2,   // (32,16,9)
    const float* __restrict__ b2,   // (32,)
    void* __restrict__ ws,
    float* __restrict__ out)        // gates(4096) + load(64)
{
    const int t = threadIdx.x;
    float* feat = (float*)ws;
    for (int i = t; i < 2048; i += 256) feat[i] = 0.0f;
    if (t >= 64 && t < 128) out[4096 + (t - 64)] = 0.0f;

    if (t < 64) {
        const int lane = t;
        const int q = lane >> 4, ml = lane & 15;
        const int n32 = lane & 31, half = lane >> 5;
        short8* F = (short8*)((char*)ws + WS_FRAG_OFF);

        // W1a (A-operand, 16x16x32): A[m=ml=oc][k=q*8+j], p=q*2+(j>>2), c=j&3
        short8 W1a;
#pragma unroll
        for (int j = 0; j < 8; ++j) {
            int p = q * 2 + (j >> 2), c = j & 3;
            W1a[j] = (c < 3) ? bf16rne(w1[ml * 27 + c * 9 + p]) : (short)0;
        }
        F[0 * 64 + lane] = W1a;

        // W1b: position 8 only, k=c (q==0, j<3); zero elsewhere
        short8 W1b;
#pragma unroll
        for (int j = 0; j < 8; ++j) {
            W1b[j] = (q == 0 && j < 3) ? bf16rne(w1[ml * 27 + j * 9 + 8])
                                       : (short)0;
        }
        F[1 * 64 + lane] = W1b;

        // conv2 B-frags (32x32x16): B[k=half*8+j=ic][n=n32=oc] = w2[(oc*16+ic)*9+s]
#pragma unroll
        for (int s = 0; s < 9; ++s) {
            short8 Bs;
#pragma unroll
            for (int j = 0; j < 8; ++j) {
                int ic = half * 8 + j;
                Bs[j] = bf16rne(w2[(n32 * 16 + ic) * 9 + s]);
            }
            F[(2 + s) * 64 + lane] = Bs;
        }
        floatx4 bv;
#pragma unroll
        for (int r = 0; r < 4; ++r) bv[r] = b1[q * 4 + r];
        ((floatx4*)((char*)ws + WS_BIAS1_OFF))[lane] = bv;
        ((float*)((char*)ws + WS_BIAS2_OFF))[lane] = b2[n32];
    }
}

// one conv1 micro-tile: 3 b64 gathers, 2 MFMA, relu, pack, b64 store to the
// lane's ic-half plane position (wptr already includes plane + (q&1)*8).
__device__ __forceinline__ void conv1_tile(
    char* __restrict__ wptr, const char* __restrict__ inb,
    const int* lcB, int gbyte, int wbyte, bool valid, bool wmask,
    short8 W1a, short8 W1b, floatx4 biasv)
{
    svec4 r0 = *(const svec4*)(inb + gbyte + lcB[0]);
    svec4 r1 = *(const svec4*)(inb + gbyte + lcB[1]);
    svec4 r2 = *(const svec4*)(inb + gbyte + lcB[2]);
    short8 Bx, By;
    Bx[0]=r0[0]; Bx[1]=r0[1]; Bx[2]=r0[2]; Bx[3]=r0[3];
    Bx[4]=r1[0]; Bx[5]=r1[1]; Bx[6]=r1[2]; Bx[7]=r1[3];
    By[0]=r2[0]; By[1]=r2[1]; By[2]=r2[2]; By[3]=r2[3];
    By[4]=r2[0]; By[5]=r2[1]; By[6]=r2[2]; By[7]=r2[3];   // W1b=0 for k>=4
    floatx4 acc = biasv;
    acc = __builtin_amdgcn_mfma_f32_16x16x32_bf16(W1a, Bx, acc, 0, 0, 0);
    acc = __builtin_amdgcn_mfma_f32_16x16x32_bf16(W1b, By, acc, 0, 0, 0);
    float v0 = fmaxf(acc[0], 0.f), v1 = fmaxf(acc[1], 0.f);
    float v2 = fmaxf(acc[2], 0.f), v3 = fmaxf(acc[3], 0.f);
    if (!valid) { v0 = 0.f; v1 = 0.f; v2 = 0.f; v3 = 0.f; }
    if (wmask) {
        uintx2 w; w.x = pk2(v0, v1); w.y = pk2(v2, v3);
        *(uintx2*)(wptr + wbyte) = w;
    }
}

// ---------------------------------------------------------------------------
// Kernel A: 32x32 output tile per block. conv1+relu (2x 16x16x32 MFMA) ->
// conv2+relu (32x32x16 MFMA, 9-shift, sliding A-window) -> spatial sum ->
// atomicAdd feat_sum[B][32]. 256 threads = 4 waves, grid (8,8,64).
// ---------------------------------------------------------------------------
__global__ __launch_bounds__(256, 3) void conv_feat_kernel(
    const float* __restrict__ x,      // (64,3,256,256)
    const void*  __restrict__ ws_ro,
    float* __restrict__ feat_sum)     // (64,32)
{
    __shared__ short s_in4[36 * 36 * 4];   // bf16 [r][col][c pad4] (10368 B)
    __shared__ short s_h1[2 * 9248];       // two ic-half planes [pix][8] (36992 B)
    __shared__ float s_part[4][32];

    const int t    = threadIdx.x;
    const int lane = t & 63, wv = t >> 6;
    const int q    = lane >> 4, ml = lane & 15;
    const int n32  = lane & 31, half = lane >> 5;
    const int tx = blockIdx.x, ty = blockIdx.y, b = blockIdx.z;
    const bool border = (tx == 0) | (tx == 7) | (ty == 0) | (ty == 7);

    // ---- weight fragments / biases ----
    const short8* F = (const short8*)((const char*)ws_ro + WS_FRAG_OFF);
    short8 W1a = F[0 * 64 + lane];
    short8 W1b = F[1 * 64 + lane];
    short8 B2[9];
#pragma unroll
    for (int s = 0; s < 9; ++s) B2[s] = F[(2 + s) * 64 + lane];
    floatx4 biasv = ((const floatx4*)((const char*)ws_ro + WS_BIAS1_OFF))[lane];
    float   b2v   = ((const float*)((const char*)ws_ro + WS_BIAS2_OFF))[lane];

    // conv1 gather byte offsets (row stride 36 px * 8 B): positions q*2,q*2+1,8
    int lcB[3];
    {
        int p0 = q * 2, p1 = q * 2 + 1;
        lcB[0] = ((p0 / 3) * 36 + p0 % 3) * 8;
        lcB[1] = ((p1 / 3) * 36 + p1 % 3) * 8;
        lcB[2] = (2 * 36 + 2) * 8;
    }

    // ---- stage input tile as bf16 [r][col][4] (halo 2) ----
    const int gy0 = ty * 32 - 2, gx0 = tx * 32 - 2;
    const float* xb = x + (size_t)b * 3 * 65536;
    if (!border) {
        for (int i = t; i < 1296; i += 256) {
            int r = i / 36, c = i - r * 36;
            const float* p = xb + (gy0 + r) * 256 + gx0 + c;
            float v0 = p[0], v1 = p[65536], v2 = p[131072];
            uintx2 w; w.x = pk2(v0, v1); w.y = pk2(v2, 0.f);
            *(uintx2*)&s_in4[i * 4] = w;
        }
    } else {
        for (int i = t; i < 1296; i += 256) {
            int r = i / 36, c = i - r * 36;
            int gy = gy0 + r, gx = gx0 + c;
            float v0 = 0.f, v1 = 0.f, v2 = 0.f;
            if ((unsigned)gy < 256u && (unsigned)gx < 256u) {
                const float* p = xb + gy * 256 + gx;
                v0 = p[0]; v1 = p[65536]; v2 = p[131072];
            }
            uintx2 w; w.x = pk2(v0, v1); w.y = pk2(v2, 0.f);
            *(uintx2*)&s_in4[i * 4] = w;
        }
    }
    __syncthreads();

    // ---- conv1 over 34x34 h1: 68 row-units + 4 col-units + corner ----
    char* wptr = (char*)s_h1 + (q >> 1) * PLANE_B + (q & 1) * 8;
    const char* inb = (const char*)s_in4;
    const int mlb = ml * 8, ml16 = ml * 16;
    if (!border) {
#pragma unroll
        for (int i = 0; i < 17; ++i) {
            int u = wv * 17 + i, row = u >> 1, ch = u & 1;
            conv1_tile(wptr, inb, lcB, row * 288 + ch * 128 + mlb,
                       row * 544 + ch * 256 + ml16, true, true,
                       W1a, W1b, biasv);
        }
        {   // col unit: col 32+(wv>>1), rows (wv&1)*16 + ml
            int col = 32 + (wv >> 1), rb = (wv & 1) * 16;
            conv1_tile(wptr, inb, lcB, (rb + ml) * 288 + col * 8,
                       ml * 544 + (rb * 34 + col) * 16, true, true,
                       W1a, W1b, biasv);
        }
        if (wv == 0) {   // corner 4 px: rows 32-33 x cols 32-33
            int ml2 = ml & 3;
            int iy = 32 + (ml2 >> 1), ix = 32 + (ml2 & 1);
            conv1_tile(wptr, inb, lcB, iy * 288 + ix * 8,
                       (iy * 34 + ix) * 16, true, ml < 4, W1a, W1b, biasv);
        }
    } else {
        const bool gxOK0 = (unsigned)(tx * 32 - 1 + ml) < 256u;
        const bool gxOK1 = (unsigned)(tx * 32 + 15 + ml) < 256u;
#pragma unroll
        for (int i = 0; i < 17; ++i) {
            int u = wv * 17 + i, row = u >> 1, ch = u & 1;
            bool ok = ((unsigned)(ty * 32 - 1 + row) < 256u) &
                      (ch ? gxOK1 : gxOK0);
            conv1_tile(wptr, inb, lcB, row * 288 + ch * 128 + mlb,
                       row * 544 + ch * 256 + ml16, ok, true,
                       W1a, W1b, biasv);
        }
        {
            int col = 32 + (wv >> 1), rb = (wv & 1) * 16;
            bool ok = ((unsigned)(ty * 32 - 1 + rb + ml) < 256u) &
                      ((unsigned)(tx * 32 - 1 + col) < 256u);
            conv1_tile(wptr, inb, lcB, (rb + ml) * 288 + col * 8,
                       ml * 544 + (rb * 34 + col) * 16, ok, true,
                       W1a, W1b, biasv);
        }
        if (wv == 0) {
            int ml2 = ml & 3;
            int iy = 32 + (ml2 >> 1), ix = 32 + (ml2 & 1);
            bool ok = ((unsigned)(ty * 32 - 1 + iy) < 256u) &
                      ((unsigned)(tx * 32 - 1 + ix) < 256u);
            conv1_tile(wptr, inb, lcB, iy * 288 + ix * 8,
                       (iy * 34 + ix) * 16, ok, ml < 4, W1a, W1b, biasv);
        }
    }
    __syncthreads();

    // ---- conv2: wave = 8 vertically-chained 32-px tiles (2 rows x 16 cols),
    //      sliding 3x3 A-frag window (ky=2 row becomes next tile's ky=0) ----
    float part = 0.0f;
    {
        const int prow0 = n32 >> 4, pcol = n32 & 15;
        const int ch = wv >> 1, tp0 = (wv & 1) * 8;
        const int ox = ch * 16 + pcol;
        const char* pl = (const char*)s_h1 + half * PLANE_B;
        int pb = ((2 * tp0 + prow0) * 34 + ox) * 16;
        short8 Af[3][3];
#pragma unroll
        for (int ky = 0; ky < 3; ++ky)
#pragma unroll
            for (int kx = 0; kx < 3; ++kx)
                Af[ky][kx] = *(const short8*)(pl + pb + (ky * 34 + kx) * 16);
#pragma unroll
        for (int it = 0; it < 8; ++it) {
            const int rb = (2 * it) % 3;
            floatx16 acc;
#pragma unroll
            for (int r = 0; r < 16; ++r) acc[r] = b2v;
#pragma unroll
            for (int s = 0; s < 9; ++s) {
                const int ky = s / 3, kx = s % 3;
                acc = __builtin_amdgcn_mfma_f32_32x32x16_bf16(
                        Af[(rb + ky) % 3][kx], B2[s], acc, 0, 0, 0);
            }
#pragma unroll
            for (int r = 0; r < 16; ++r) part += fmaxf(acc[r], 0.0f);
            if (it < 7) {
                pb += 1088;   // advance 2 h1 rows
#pragma unroll
                for (int kx = 0; kx < 3; ++kx) {
                    Af[rb][kx] =
                        *(const short8*)(pl + pb + (1 * 34 + kx) * 16);
                    Af[(rb + 1) % 3][kx] =
                        *(const short8*)(pl + pb + (2 * 34 + kx) * 16);
                }
            }
        }
    }
    part += __shfl_xor(part, 32);
    if (lane < 32) s_part[wv][n32] = part;
    __syncthreads();
    if (t < 32) {
        float ssum = s_part[0][t] + s_part[1][t] + s_part[2][t] + s_part[3][t];
        atomicAdd(feat_sum + b * 32 + t, ssum);
    }
}

// ---------------------------------------------------------------------------
// Kernel B: gating. One block per batch row, 64 threads (= experts, 1 wave).
// ---------------------------------------------------------------------------
__global__ __launch_bounds__(64) void router_gate_kernel(
    const int* __restrict__ task_id,
    const float* __restrict__ noise,
    const float* __restrict__ mlp_w1,
    const float* __restrict__ mlp_b1,
    const float* __restrict__ mlp_w2,
    const float* __restrict__ mlp_b2,
    const float* __restrict__ deg_w,
    const float* __restrict__ deg_b,
    const float* __restrict__ keys,
    const float* __restrict__ gate_w,
    const float* __restrict__ gate_b,
    const float* __restrict__ noise_w,
    const float* __restrict__ noise_b,
    const float* __restrict__ feat_sum,
    float* __restrict__ out)
{
    const int b = blockIdx.x;
    const int e = threadIdx.x;

    __shared__ float s_te[32];
    __shared__ float s_comb[32];
    __shared__ float s_ew[64];

    if (e < 32) {
        float tf = (float)task_id[b];
        s_te[e] = fmaxf(tf * mlp_w1[e] + mlp_b1[e], 0.0f);
    }
    __syncthreads();
    if (e < 32) {
        float acc = mlp_b2[e];
        for (int k = 0; k < 32; ++k) acc += s_te[k] * mlp_w2[k * 32 + e];
        float dacc = deg_b[e];
        for (int c = 0; c < 32; ++c)
            dacc += (feat_sum[b * 32 + c] * (1.0f / 65536.0f)) * deg_w[c * 32 + e];
        s_comb[e] = acc + 0.2f * dacc;  // ALPHA = 0.8
    }
    __syncthreads();

    float s = 0.0f;
    for (int d = 0; d < 32; ++d) s += s_comb[d] * keys[e * 32 + d];
    s *= 0.17677669529663687f;  // 1/sqrt(32)

    float m = s;
    for (int off = 32; off; off >>= 1) m = fmaxf(m, __shfl_xor(m, off));
    float p = expf(s - m);
    float sum = p;
    for (int off = 32; off; off >>= 1) sum += __shfl_xor(sum, off);
    float w = p / sum;
    s_ew[e] = w;
    __syncthreads();

    float cl = gate_b[e], nz = noise_b[e];
    for (int k = 0; k < 64; ++k) {
        float ewk = s_ew[k];
        cl += ewk * gate_w[k * 64 + e];
        nz += ewk * noise_w[k * 64 + e];
    }
    float sp = (nz > 20.0f) ? nz : log1pf(expf(nz));
    float logit = cl + noise[b * 64 + e] * (sp + 0.01f);

    float v0 = logit; int i0 = e;
    for (int off = 32; off; off >>= 1) {
        float ov = __shfl_xor(v0, off);
        int   oi = __shfl_xor(i0, off);
        if (ov > v0 || (ov == v0 && oi < i0)) { v0 = ov; i0 = oi; }
    }
    float v1 = (e == i0) ? -INFINITY : logit; int i1 = e;
    for (int off = 32; off; off >>= 1) {
        float ov = __shfl_xor(v1, off);
        int   oi = __shfl_xor(i1, off);
        if (ov > v1 || (ov == v1 && oi < i1)) { v1 = ov; i1 = oi; }
    }

    float e1 = expf(v1 - v0);
    float g0 = 1.0f / (1.0f + e1);
    float g1 = e1 / (1.0f + e1);

    float g = (e == i0) ? g0 : (e == i1) ? g1 : 0.0f;
    out[b * 64 + e] = g;
    if (g != 0.0f) atomicAdd(out + 64 * 64 + e, g);
}

extern "C" void kernel_launch(void* const* d_in, const int* in_sizes, int n_in,
                              void* d_out, int out_size, void* d_ws, size_t ws_size,
                              hipStream_t stream) {
    const int*   task_id = (const int*)d_in[0];
    const float* x       = (const float*)d_in[1];
    const float* noise   = (const float*)d_in[2];
    const float* mlp_w1  = (const float*)d_in[3];
    const float* mlp_b1  = (const float*)d_in[4];
    const float* mlp_w2  = (const float*)d_in[5];
    const float* mlp_b2  = (const float*)d_in[6];
    const float* conv1_w = (const float*)d_in[7];
    const float* conv1_b = (const float*)d_in[8];
    const float* conv2_w = (const float*)d_in[9];
    const float* conv2_b = (const float*)d_in[10];
    const float* deg_w   = (const float*)d_in[11];
    const float* deg_b   = (const float*)d_in[12];
    const float* keys    = (const float*)d_in[13];
    const float* gate_w  = (const float*)d_in[14];
    const float* gate_b  = (const float*)d_in[15];
    const float* noise_w = (const float*)d_in[16];
    const float* noise_b = (const float*)d_in[17];

    float* out  = (float*)d_out;
    float* feat = (float*)d_ws;

    build_frags_kernel<<<1, 256, 0, stream>>>(conv1_w, conv1_b, conv2_w,
                                              conv2_b, d_ws, out);
    dim3 gridA(8, 8, 64);
    conv_feat_kernel<<<gridA, 256, 0, stream>>>(x, d_ws, feat);
    router_gate_kernel<<<64, 64, 0, stream>>>(
        task_id, noise, mlp_w1, mlp_b1, mlp_w2, mlp_b2, deg_w, deg_b, keys,
        gate_w, gate_b, noise_w, noise_b, feat, out);
}